// Round 4
// baseline (15465.150 us; speedup 1.0000x reference)
//
#include <hip/hip_runtime.h>
#include <math.h>

#define BB_ 32
#define TT_ 128
#define EE_ 64
#define HH_ 128
#define VV_ 32000
#define NMM 200      // matmul workgroups
#define NCELL 32     // cell workgroups (one per batch)
#define NWG (NMM + NCELL)
#define VW 160       // vocab rows per matmul wg (200*160 = 32000)

// ---- dynamic LDS layout (bytes) for matmul wgs ----
#define LHB_STRIDE 136              // floats per batch row (128 + pad)
#define OFF_LHB 0                   // float[32*136] = 17408  h tile, [b][k]
#define OFF_RDF 17408               // float[3*128*41] = 62976  k-split reduce (stride 41 dwords)
// cell wgs overlay (same dynamic buffer, different CUs)
#define OFF_SG  0                   // float[512] gates
#define OFF_SH  2048                // float[128] h
#define OFF_TOK 2560                // int token broadcast
#define DYN_LDS 98304               // 96KB: forces 1 wg/CU (160KB pool)

// ---- workspace layout (bytes) ----
#define WS_GBEST 0                  // u64[129*32] = 33024  per-(step,batch) argmax (packed)
#define WS_HCNT  33024              // u32[160] = 640       cells done with step s
#define WS_MCNT  33664              // u32[160] = 640       matmuls done with step s
#define WS_ZEND  34304              // zero [0, WS_ZEND) each launch
#define WS_HDEC  34304              // float[32*128]
#define WS_HENC  50688              // float[32*128]
#define WS_CENC  67072              // float[32*128]
#define WS_END   83456

__device__ __forceinline__ float rlane(float v, int l){
  return __int_as_float(__builtin_amdgcn_readlane(__float_as_int(v), l));
}
__device__ __forceinline__ float sigm(float x){ return 1.f / (1.f + expf(-x)); }

__device__ __forceinline__ unsigned long long packmax(float v, int idx){
  unsigned u = __float_as_uint(v);
  u = (u & 0x80000000u) ? ~u : (u | 0x80000000u);   // monotone float->uint map
  return ((unsigned long long)u << 32) | (unsigned long long)(0xFFFFFFFFu - (unsigned)idx);
}

template <int SLP>
__device__ __forceinline__ void wait_eq(const unsigned* p, unsigned v){
  while (__hip_atomic_load(p, __ATOMIC_ACQUIRE, __HIP_MEMORY_SCOPE_AGENT) != v)
    __builtin_amdgcn_s_sleep(SLP);
}

// gate[row=t] = bias + sum_e wih[e]*x[e] + sum_j whh[j]*h[j]; x/h broadcast via readlane
__device__ __forceinline__ float gate_dot(const float (&wih)[EE_], const float (&whh)[HH_],
                                          float bias, float xe, float h0, float h1){
  float a0 = bias, a1 = 0.f, a2 = 0.f, a3 = 0.f;
#pragma unroll
  for (int e = 0; e < EE_; e += 4){
    a0 = fmaf(wih[e+0], rlane(xe, e+0), a0);
    a1 = fmaf(wih[e+1], rlane(xe, e+1), a1);
    a2 = fmaf(wih[e+2], rlane(xe, e+2), a2);
    a3 = fmaf(wih[e+3], rlane(xe, e+3), a3);
  }
#pragma unroll
  for (int j = 0; j < 64; j += 4){
    a0 = fmaf(whh[j+0], rlane(h0, j+0), a0);
    a1 = fmaf(whh[j+1], rlane(h0, j+1), a1);
    a2 = fmaf(whh[j+2], rlane(h0, j+2), a2);
    a3 = fmaf(whh[j+3], rlane(h0, j+3), a3);
  }
#pragma unroll
  for (int j = 0; j < 64; j += 4){
    a0 = fmaf(whh[64+j+0], rlane(h1, j+0), a0);
    a1 = fmaf(whh[64+j+1], rlane(h1, j+1), a1);
    a2 = fmaf(whh[64+j+2], rlane(h1, j+2), a2);
    a3 = fmaf(whh[64+j+3], rlane(h1, j+3), a3);
  }
  return (a0 + a1) + (a2 + a3);
}

// ===================== encoder: 32 wgs (one per batch), no cross-wg deps =====================
__global__ __launch_bounds__(512) __attribute__((amdgpu_waves_per_eu(2, 2)))
void enc_kernel(const int* __restrict__ xt, const float* __restrict__ embed,
                const float* __restrict__ Wih, const float* __restrict__ Whh,
                const float* __restrict__ bv,
                float* __restrict__ h_out, float* __restrict__ c_out)
{
  const int b = blockIdx.x, t = threadIdx.x, lane = t & 63;
  __shared__ float sh[HH_];
  __shared__ float sg[4*HH_];
  float wih[EE_], whh[HH_];
#pragma unroll
  for (int e = 0; e < EE_; ++e) wih[e] = Wih[t*EE_ + e];
#pragma unroll
  for (int j = 0; j < HH_; ++j) whh[j] = Whh[t*HH_ + j];
  const float bias = bv[t];
  float c = 0.f, hv = 0.f;
  if (t < HH_) sh[t] = 0.f;
  __syncthreads();
#pragma unroll 1
  for (int s = 0; s < TT_; ++s){
    const int tok = xt[b*TT_ + s];
    const float xe = embed[tok*EE_ + lane];
    const float h0 = sh[lane], h1 = sh[64 + lane];
    const float g = gate_dot(wih, whh, bias, xe, h0, h1);
    __syncthreads();   // sh reads done before writes below
    sg[t] = g;
    __syncthreads();
    if (t < HH_){
      const float gi = sg[t], gf = sg[128+t], gg = sg[256+t], go = sg[384+t];
      c = sigm(gf)*c + sigm(gi)*tanhf(gg);
      hv = sigm(go)*tanhf(c);
      sh[t] = hv;
    }
    __syncthreads();
  }
  if (t < HH_){ h_out[b*HH_ + t] = hv; c_out[b*HH_ + t] = c; }
}

// ===================== decoder: persistent, 32 cell wgs + 200 matmul wgs =====================
__global__ __launch_bounds__(512) __attribute__((amdgpu_waves_per_eu(2, 2)))
void dec_kernel(const float* __restrict__ embed,
                const float* __restrict__ dWih, const float* __restrict__ dWhh,
                const float* __restrict__ db,
                const float* __restrict__ fcw, const float* __restrict__ fcb,
                const float* __restrict__ h_enc, const float* __restrict__ c_enc,
                float* __restrict__ h_dec, unsigned long long* __restrict__ gbest,
                unsigned* __restrict__ hcnt, unsigned* __restrict__ mcnt,
                float* __restrict__ out)
{
  extern __shared__ char smem[];
  const int t = threadIdx.x;
  const int wg = blockIdx.x;

  if (wg < NCELL){
    // ---------------- cell workgroup: owns batch b ----------------
    float* sg = (float*)(smem + OFF_SG);
    float* sh = (float*)(smem + OFF_SH);
    int* stok = (int*)(smem + OFF_TOK);
    const int b = wg, lane = t & 63;
    float wih[EE_], whh[HH_];
#pragma unroll
    for (int e = 0; e < EE_; ++e) wih[e] = dWih[t*EE_ + e];
#pragma unroll
    for (int j = 0; j < HH_; ++j) whh[j] = dWhh[t*HH_ + j];
    const float bias = db[t];
    float c = 0.f;
    if (t < HH_){ c = c_enc[b*HH_ + t]; sh[t] = h_enc[b*HH_ + t]; }
    int tok = 1; // SOS
    __syncthreads();
#pragma unroll 1
    for (int s = 1; s <= TT_; ++s){
      const float xe = embed[tok*EE_ + lane];
      const float h0 = sh[lane], h1 = sh[64 + lane];
      const float g = gate_dot(wih, whh, bias, xe, h0, h1);
      sg[t] = g;
      __syncthreads();
      if (t < HH_){
        const float gi = sg[t], gf = sg[128+t], gg = sg[256+t], go = sg[384+t];
        c = sigm(gf)*c + sigm(gi)*tanhf(gg);
        const float hv = sigm(go)*tanhf(c);
        sh[t] = hv;
        __hip_atomic_store(&h_dec[b*HH_ + t], hv, __ATOMIC_RELAXED, __HIP_MEMORY_SCOPE_AGENT);
      }
      __threadfence();          // drain h stores to coherence point
      __syncthreads();
      if (t == 0){
        __hip_atomic_fetch_add(&hcnt[s], 1u, __ATOMIC_RELEASE, __HIP_MEMORY_SCOPE_AGENT);
        wait_eq<2>(&mcnt[s], (unsigned)NMM);
        const unsigned long long gbv =
            __hip_atomic_load(&gbest[(size_t)s*BB_ + b], __ATOMIC_RELAXED, __HIP_MEMORY_SCOPE_AGENT);
        *stok = (int)(0xFFFFFFFFu - (unsigned)(gbv & 0xFFFFFFFFull));
      }
      __syncthreads();
      tok = *stok;
    }
  } else {
    // ---------------- matmul workgroup: vocab rows [v0, v0+VW) ----------------
    const int widx = wg - NCELL;
    const int v0 = widx * VW;
    float* lhb = (float*)(smem + OFF_LHB);
    float* rdf = (float*)(smem + OFF_RDF);
    const int ks = t >> 7;          // k-split quarter: k in [ks*32, ks*32+32)
    const int u  = t & 127;
    const int vg = u & 31;          // vocab lane; row v = v0 + vi*32 + vg
    const int bg = u >> 5;          // batch group (8 batches each)
    // fc_w fragment lives in REGISTERS for all 128 steps (40 float4 = 160 VGPR)
    float4 wreg[8][5];
#pragma unroll
    for (int vi = 0; vi < 5; ++vi){
      const float4* fw4 = (const float4*)(fcw + (size_t)(v0 + vi*32 + vg)*HH_ + ks*32);
#pragma unroll
      for (int kc = 0; kc < 8; ++kc) wreg[kc][vi] = fw4[kc];
    }
    float fb[5];
#pragma unroll
    for (int vi = 0; vi < 5; ++vi) fb[vi] = fcb[v0 + vi*32 + vg];
    const unsigned long long* hd64 = (const unsigned long long*)h_dec;
    __syncthreads();
#pragma unroll 1
    for (int s = 1; s <= TT_; ++s){
      if (t == 0) wait_eq<4>(&hcnt[s], (unsigned)NCELL);
      __syncthreads();
      // stage h into LDS [b][k] (device-scope loads bypass stale caches)
#pragma unroll
      for (int i = t; i < BB_*HH_/2; i += 512){
        const unsigned long long v =
            __hip_atomic_load(hd64 + i, __ATOMIC_RELAXED, __HIP_MEMORY_SCOPE_AGENT);
        const int bb = i >> 6, k2 = (i & 63)*2;
        float2 f;
        f.x = __uint_as_float((unsigned)(v & 0xFFFFFFFFull));
        f.y = __uint_as_float((unsigned)(v >> 32));
        *(float2*)&lhb[bb*LHB_STRIDE + k2] = f;
      }
      __syncthreads();
      float acc[5][8];
#pragma unroll
      for (int vi = 0; vi < 5; ++vi)
#pragma unroll
        for (int bi = 0; bi < 8; ++bi) acc[vi][bi] = 0.f;
#pragma unroll
      for (int kc = 0; kc < 8; ++kc){
        const int kk = ks*32 + kc*4;
#pragma unroll
        for (int bi = 0; bi < 8; ++bi){
          const float4 hb = *(const float4*)&lhb[(bg*8 + bi)*LHB_STRIDE + kk];  // broadcast read
#pragma unroll
          for (int vi = 0; vi < 5; ++vi){
            const float4 w = wreg[kc][vi];
            acc[vi][bi] = fmaf(w.x,hb.x,fmaf(w.y,hb.y,fmaf(w.z,hb.z,fmaf(w.w,hb.w,acc[vi][bi]))));
          }
        }
      }
      // k-split reduce: ks=1..3 publish, ks=0 combines (stride-41 dwords: <=2-way banks)
      if (ks){
        float* dst = rdf + ((size_t)(ks-1)*128 + u)*41;
#pragma unroll
        for (int vi = 0; vi < 5; ++vi)
#pragma unroll
          for (int bi = 0; bi < 8; ++bi) dst[vi*8 + bi] = acc[vi][bi];
      }
      __syncthreads();
      if (ks == 0){
#pragma unroll
        for (int r = 0; r < 3; ++r){
          const float* src = rdf + ((size_t)r*128 + u)*41;
#pragma unroll
          for (int vi = 0; vi < 5; ++vi)
#pragma unroll
            for (int bi = 0; bi < 8; ++bi) acc[vi][bi] += src[vi*8 + bi];
        }
#pragma unroll
        for (int vi = 0; vi < 5; ++vi)
#pragma unroll
          for (int bi = 0; bi < 8; ++bi) acc[vi][bi] += fb[vi];
        // per-batch argmax over this wg's 160 rows: 5 local + butterfly over 32 vocab lanes
#pragma unroll
        for (int bi = 0; bi < 8; ++bi){
          unsigned long long best = 0ull;
#pragma unroll
          for (int vi = 0; vi < 5; ++vi){
            const unsigned long long pk = packmax(acc[vi][bi], v0 + vi*32 + vg);
            if (pk > best) best = pk;
          }
#pragma unroll
          for (int off = 16; off > 0; off >>= 1){
            const unsigned long long o = __shfl_xor(best, off);
            if (o > best) best = o;
          }
          if (vg == 0)
            __hip_atomic_fetch_max(&gbest[(size_t)s*BB_ + bg*8 + bi], best,
                                   __ATOMIC_RELAXED, __HIP_MEMORY_SCOPE_AGENT);
        }
      }
      __threadfence();            // atomicMax results visible before the count bump
      __syncthreads();
      if (t == 0)
        __hip_atomic_fetch_add(&mcnt[s], 1u, __ATOMIC_RELEASE, __HIP_MEMORY_SCOPE_AGENT);
      // logits written AFTER the handshake (nontemporal: keep L2 for coherence traffic)
      if (ks == 0){
#pragma unroll
        for (int bi = 0; bi < 8; ++bi){
          float* orow = out + ((size_t)(bg*8 + bi)*TT_ + (s-1))*(size_t)VV_ + v0;
#pragma unroll
          for (int vi = 0; vi < 5; ++vi)
            __builtin_nontemporal_store(acc[vi][bi], &orow[vi*32 + vg]);
        }
      }
    }
  }
}

extern "C" void kernel_launch(void* const* d_in, const int* in_sizes, int n_in,
                              void* d_out, int out_size, void* d_ws, size_t ws_size,
                              hipStream_t stream){
  (void)in_sizes; (void)n_in; (void)out_size; (void)ws_size;
  const int*   x     = (const int*)  d_in[0];
  const float* embed = (const float*)d_in[1];
  const float* eWih  = (const float*)d_in[2];
  const float* eWhh  = (const float*)d_in[3];
  const float* eb    = (const float*)d_in[4];
  const float* dWih  = (const float*)d_in[5];
  const float* dWhh  = (const float*)d_in[6];
  const float* db    = (const float*)d_in[7];
  const float* fcw   = (const float*)d_in[8];
  const float* fcb   = (const float*)d_in[9];
  float* out = (float*)d_out;
  char* ws = (char*)d_ws;
  unsigned long long* gbest = (unsigned long long*)(ws + WS_GBEST);
  unsigned* hcnt = (unsigned*)(ws + WS_HCNT);
  unsigned* mcnt = (unsigned*)(ws + WS_MCNT);
  float* h_dec = (float*)(ws + WS_HDEC);
  float* h_enc = (float*)(ws + WS_HENC);
  float* c_enc = (float*)(ws + WS_CENC);

  // zero handshake state every launch (graph node -> deterministic replays)
  (void)hipMemsetAsync(ws, 0, WS_ZEND, stream);
  // allow >64KB dynamic LDS (gfx950 has 160KB/CU); idempotent host-side call
  (void)hipFuncSetAttribute((const void*)dec_kernel, hipFuncAttributeMaxDynamicSharedMemorySize, DYN_LDS);

  enc_kernel<<<NCELL, 512, 0, stream>>>(x, embed, eWih, eWhh, eb, h_enc, c_enc);
  dec_kernel<<<NWG, 512, DYN_LDS, stream>>>(embed, dWih, dWhh, db, fcw, fcb,
                                            h_enc, c_enc, h_dec, gbest, hcnt, mcnt, out);
}

// Round 5
// 12885.532 us; speedup vs baseline: 1.2002x; 1.2002x over previous
//
#include <hip/hip_runtime.h>
#include <math.h>

#define BB_ 32
#define TT_ 128
#define EE_ 64
#define HH_ 128
#define VV_ 32000
#define NMM 200      // matmul workgroups
#define NCELL 32     // cell workgroups (one per batch)
#define NWG (NMM + NCELL)
#define VW 160       // vocab rows per matmul wg (200*160 = 32000)

// ---- dynamic LDS layout (bytes) for matmul wgs ----
#define OFF_LW  0                   // float4[32 kcc][160 r] = 81920  fc_w slice
#define OFF_LHB 81920               // float[32 b][128 k]    = 16384  h tile
#define OFF_RDF 98304               // float[3*128 slots]*41 = 62976  k-split reduce (stride 41: conflict-free)
// cell wgs overlay (same dynamic buffer, different CUs)
#define OFF_SG  0                   // float[512] gates
#define OFF_SH  2048                // float[128] h
#define OFF_TOK 2560                // int token broadcast
#define DYN_LDS 161280              // 157.5KB -> 1 wg/CU (160KB pool)

// ---- workspace layout (bytes) ----
#define WS_GBEST 0                  // u64[129*32] = 33024  per-(step,batch) argmax (packed)
#define WS_HCNT  33024              // u32[160] = 640       cells done with step s
#define WS_MCNT  33664              // u32[160] = 640       matmuls done with step s
#define WS_ZEND  34304              // zero [0, WS_ZEND) each launch
#define WS_HDEC  34304              // float[32*128]
#define WS_HENC  50688              // float[32*128]
#define WS_CENC  67072              // float[32*128]
#define WS_END   83456

__device__ __forceinline__ float rlane(float v, int l){
  return __int_as_float(__builtin_amdgcn_readlane(__float_as_int(v), l));
}
__device__ __forceinline__ float sigm(float x){ return 1.f / (1.f + expf(-x)); }

__device__ __forceinline__ unsigned long long packmax(float v, int idx){
  unsigned u = __float_as_uint(v);
  u = (u & 0x80000000u) ? ~u : (u | 0x80000000u);   // monotone float->uint map
  return ((unsigned long long)u << 32) | (unsigned long long)(0xFFFFFFFFu - (unsigned)idx);
}

template <int SLP>
__device__ __forceinline__ void wait_eq(const unsigned* p, unsigned v){
  while (__hip_atomic_load(p, __ATOMIC_ACQUIRE, __HIP_MEMORY_SCOPE_AGENT) != v)
    __builtin_amdgcn_s_sleep(SLP);
}

// gate[row=t] = bias + sum_e wih[e]*x[e] + sum_j whh[j]*h[j]; x/h broadcast via readlane
__device__ __forceinline__ float gate_dot(const float (&wih)[EE_], const float (&whh)[HH_],
                                          float bias, float xe, float h0, float h1){
  float a0 = bias, a1 = 0.f, a2 = 0.f, a3 = 0.f;
#pragma unroll
  for (int e = 0; e < EE_; e += 4){
    a0 = fmaf(wih[e+0], rlane(xe, e+0), a0);
    a1 = fmaf(wih[e+1], rlane(xe, e+1), a1);
    a2 = fmaf(wih[e+2], rlane(xe, e+2), a2);
    a3 = fmaf(wih[e+3], rlane(xe, e+3), a3);
  }
#pragma unroll
  for (int j = 0; j < 64; j += 4){
    a0 = fmaf(whh[j+0], rlane(h0, j+0), a0);
    a1 = fmaf(whh[j+1], rlane(h0, j+1), a1);
    a2 = fmaf(whh[j+2], rlane(h0, j+2), a2);
    a3 = fmaf(whh[j+3], rlane(h0, j+3), a3);
  }
#pragma unroll
  for (int j = 0; j < 64; j += 4){
    a0 = fmaf(whh[64+j+0], rlane(h1, j+0), a0);
    a1 = fmaf(whh[64+j+1], rlane(h1, j+1), a1);
    a2 = fmaf(whh[64+j+2], rlane(h1, j+2), a2);
    a3 = fmaf(whh[64+j+3], rlane(h1, j+3), a3);
  }
  return (a0 + a1) + (a2 + a3);
}

// ===================== encoder: 32 wgs (one per batch), no cross-wg deps =====================
__global__ __launch_bounds__(512)
void enc_kernel(const int* __restrict__ xt, const float* __restrict__ embed,
                const float* __restrict__ Wih, const float* __restrict__ Whh,
                const float* __restrict__ bv,
                float* __restrict__ h_out, float* __restrict__ c_out)
{
  const int b = blockIdx.x, t = threadIdx.x, lane = t & 63;
  __shared__ float sh[HH_];
  __shared__ float sg[4*HH_];
  float wih[EE_], whh[HH_];
#pragma unroll
  for (int e = 0; e < EE_; ++e) wih[e] = Wih[t*EE_ + e];
#pragma unroll
  for (int j = 0; j < HH_; ++j) whh[j] = Whh[t*HH_ + j];
  const float bias = bv[t];
  float c = 0.f, hv = 0.f;
  if (t < HH_) sh[t] = 0.f;
  __syncthreads();
#pragma unroll 1
  for (int s = 0; s < TT_; ++s){
    const int tok = xt[b*TT_ + s];
    const float xe = embed[tok*EE_ + lane];
    const float h0 = sh[lane], h1 = sh[64 + lane];
    const float g = gate_dot(wih, whh, bias, xe, h0, h1);
    __syncthreads();   // sh reads done before writes below
    sg[t] = g;
    __syncthreads();
    if (t < HH_){
      const float gi = sg[t], gf = sg[128+t], gg = sg[256+t], go = sg[384+t];
      c = sigm(gf)*c + sigm(gi)*tanhf(gg);
      hv = sigm(go)*tanhf(c);
      sh[t] = hv;
    }
    __syncthreads();
  }
  if (t < HH_){ h_out[b*HH_ + t] = hv; c_out[b*HH_ + t] = c; }
}

// ===================== decoder: persistent, 32 cell wgs + 200 matmul wgs =====================
__global__ __launch_bounds__(512)
void dec_kernel(const float* __restrict__ embed,
                const float* __restrict__ dWih, const float* __restrict__ dWhh,
                const float* __restrict__ db,
                const float* __restrict__ fcw, const float* __restrict__ fcb,
                const float* __restrict__ h_enc, const float* __restrict__ c_enc,
                float* __restrict__ h_dec, unsigned long long* __restrict__ gbest,
                unsigned* __restrict__ hcnt, unsigned* __restrict__ mcnt,
                float* __restrict__ out)
{
  extern __shared__ char smem[];
  const int t = threadIdx.x;
  const int wg = blockIdx.x;

  if (wg < NCELL){
    // ---------------- cell workgroup: owns batch b ----------------
    float* sg = (float*)(smem + OFF_SG);
    float* sh = (float*)(smem + OFF_SH);
    int* stok = (int*)(smem + OFF_TOK);
    const int b = wg, lane = t & 63;
    float wih[EE_], whh[HH_];
#pragma unroll
    for (int e = 0; e < EE_; ++e) wih[e] = dWih[t*EE_ + e];
#pragma unroll
    for (int j = 0; j < HH_; ++j) whh[j] = dWhh[t*HH_ + j];
    const float bias = db[t];
    float c = 0.f;
    if (t < HH_){ c = c_enc[b*HH_ + t]; sh[t] = h_enc[b*HH_ + t]; }
    int tok = 1; // SOS
    __syncthreads();
#pragma unroll 1
    for (int s = 1; s <= TT_; ++s){
      const float xe = embed[tok*EE_ + lane];
      const float h0 = sh[lane], h1 = sh[64 + lane];
      const float g = gate_dot(wih, whh, bias, xe, h0, h1);
      sg[t] = g;
      __syncthreads();
      if (t < HH_){
        const float gi = sg[t], gf = sg[128+t], gg = sg[256+t], go = sg[384+t];
        c = sigm(gf)*c + sigm(gi)*tanhf(gg);
        const float hv = sigm(go)*tanhf(c);
        sh[t] = hv;
        __hip_atomic_store(&h_dec[b*HH_ + t], hv, __ATOMIC_RELAXED, __HIP_MEMORY_SCOPE_AGENT);
      }
      __threadfence();          // drain h stores to coherence point
      __syncthreads();
      if (t == 0){
        __hip_atomic_fetch_add(&hcnt[s], 1u, __ATOMIC_RELEASE, __HIP_MEMORY_SCOPE_AGENT);
        wait_eq<2>(&mcnt[s], (unsigned)NMM);
        const unsigned long long gbv =
            __hip_atomic_load(&gbest[(size_t)s*BB_ + b], __ATOMIC_RELAXED, __HIP_MEMORY_SCOPE_AGENT);
        *stok = (int)(0xFFFFFFFFu - (unsigned)(gbv & 0xFFFFFFFFull));
      }
      __syncthreads();
      tok = *stok;
    }
  } else {
    // ---------------- matmul workgroup: vocab rows [v0, v0+VW) ----------------
    const int widx = wg - NCELL;
    const int v0 = widx * VW;
    float4* lw4 = (float4*)(smem + OFF_LW);   // [kcc][r]
    float*  lhb = (float*)(smem + OFF_LHB);   // [b][k], stride 128
    float*  rdf = (float*)(smem + OFF_RDF);
    const int ks = t >> 7;          // k-split quarter: k in [ks*32, ks*32+32)
    const int u  = t & 127;
    const int vg = u & 31;          // vocab lane; row v = v0 + vi*32 + vg
    const int bg = u >> 5;          // batch group (8 batches each)
    // stage fc_w slice into LDS once (reused for all 128 steps)
    for (int i = t; i < VW*HH_; i += 512){
      const int r = i >> 7, k = i & 127;
      ((float*)lw4)[((k >> 2)*VW + r)*4 + (k & 3)] = fcw[(size_t)(v0 + r)*HH_ + k];
    }
    float fb[5];
#pragma unroll
    for (int vi = 0; vi < 5; ++vi) fb[vi] = fcb[v0 + vi*32 + vg];
    const unsigned long long* hd64 = (const unsigned long long*)h_dec;
    __syncthreads();
#pragma unroll 1
    for (int s = 1; s <= TT_; ++s){
      if (t == 0) wait_eq<4>(&hcnt[s], (unsigned)NCELL);
      __syncthreads();
      // stage h into LDS [b][k] (device-scope loads bypass stale caches)
#pragma unroll
      for (int i = t; i < BB_*HH_/2; i += 512){
        const unsigned long long v =
            __hip_atomic_load(hd64 + i, __ATOMIC_RELAXED, __HIP_MEMORY_SCOPE_AGENT);
        const int bb = i >> 6, k2 = (i & 63)*2;
        float2 f;
        f.x = __uint_as_float((unsigned)(v & 0xFFFFFFFFull));
        f.y = __uint_as_float((unsigned)(v >> 32));
        *(float2*)&lhb[bb*HH_ + k2] = f;
      }
      __syncthreads();
      float acc[5][8];
#pragma unroll
      for (int vi = 0; vi < 5; ++vi)
#pragma unroll
        for (int bi = 0; bi < 8; ++bi) acc[vi][bi] = 0.f;
      const int kb = ks * 8;      // 8 float4-chunks (32 k) per ks
#pragma unroll
      for (int kc = 0; kc < 8; ++kc){
        const int kcc = kb + kc;
        float4 w[5];
#pragma unroll
        for (int vi = 0; vi < 5; ++vi) w[vi] = lw4[kcc*VW + vi*32 + vg];  // read ONCE per kc
#pragma unroll
        for (int bi = 0; bi < 8; ++bi){
          const float4 hb = *(const float4*)&lhb[(bg*8 + bi)*HH_ + kcc*4];  // broadcast read
#pragma unroll
          for (int vi = 0; vi < 5; ++vi)
            acc[vi][bi] = fmaf(w[vi].x,hb.x,fmaf(w[vi].y,hb.y,fmaf(w[vi].z,hb.z,fmaf(w[vi].w,hb.w,acc[vi][bi]))));
        }
      }
      // k-split reduce: ks=1..3 publish, ks=0 combines (stride-41 dwords: <=2-way banks)
      if (ks){
        float* dst = rdf + ((size_t)(ks-1)*128 + u)*41;
#pragma unroll
        for (int vi = 0; vi < 5; ++vi)
#pragma unroll
          for (int bi = 0; bi < 8; ++bi) dst[vi*8 + bi] = acc[vi][bi];
      }
      __syncthreads();
      if (ks == 0){
#pragma unroll
        for (int r = 0; r < 3; ++r){
          const float* src = rdf + ((size_t)r*128 + u)*41;
#pragma unroll
          for (int vi = 0; vi < 5; ++vi)
#pragma unroll
            for (int bi = 0; bi < 8; ++bi) acc[vi][bi] += src[vi*8 + bi];
        }
#pragma unroll
        for (int vi = 0; vi < 5; ++vi)
#pragma unroll
          for (int bi = 0; bi < 8; ++bi) acc[vi][bi] += fb[vi];
        // per-batch argmax over this wg's 160 rows: 5 local + butterfly over 32 vocab lanes
#pragma unroll
        for (int bi = 0; bi < 8; ++bi){
          unsigned long long best = 0ull;
#pragma unroll
          for (int vi = 0; vi < 5; ++vi){
            const unsigned long long pk = packmax(acc[vi][bi], v0 + vi*32 + vg);
            if (pk > best) best = pk;
          }
#pragma unroll
          for (int off = 16; off > 0; off >>= 1){
            const unsigned long long o = __shfl_xor(best, off);
            if (o > best) best = o;
          }
          if (vg == 0)
            __hip_atomic_fetch_max(&gbest[(size_t)s*BB_ + bg*8 + bi], best,
                                   __ATOMIC_RELAXED, __HIP_MEMORY_SCOPE_AGENT);
        }
      }
      __threadfence();            // atomicMax results visible before the count bump
      __syncthreads();
      if (t == 0)
        __hip_atomic_fetch_add(&mcnt[s], 1u, __ATOMIC_RELEASE, __HIP_MEMORY_SCOPE_AGENT);
      // logits written AFTER the handshake (nontemporal: keep L2 for coherence traffic)
      if (ks == 0){
#pragma unroll
        for (int bi = 0; bi < 8; ++bi){
          float* orow = out + ((size_t)(bg*8 + bi)*TT_ + (s-1))*(size_t)VV_ + v0;
#pragma unroll
          for (int vi = 0; vi < 5; ++vi)
            __builtin_nontemporal_store(acc[vi][bi], &orow[vi*32 + vg]);
        }
      }
    }
  }
}

extern "C" void kernel_launch(void* const* d_in, const int* in_sizes, int n_in,
                              void* d_out, int out_size, void* d_ws, size_t ws_size,
                              hipStream_t stream){
  (void)in_sizes; (void)n_in; (void)out_size; (void)ws_size;
  const int*   x     = (const int*)  d_in[0];
  const float* embed = (const float*)d_in[1];
  const float* eWih  = (const float*)d_in[2];
  const float* eWhh  = (const float*)d_in[3];
  const float* eb    = (const float*)d_in[4];
  const float* dWih  = (const float*)d_in[5];
  const float* dWhh  = (const float*)d_in[6];
  const float* db    = (const float*)d_in[7];
  const float* fcw   = (const float*)d_in[8];
  const float* fcb   = (const float*)d_in[9];
  float* out = (float*)d_out;
  char* ws = (char*)d_ws;
  unsigned long long* gbest = (unsigned long long*)(ws + WS_GBEST);
  unsigned* hcnt = (unsigned*)(ws + WS_HCNT);
  unsigned* mcnt = (unsigned*)(ws + WS_MCNT);
  float* h_dec = (float*)(ws + WS_HDEC);
  float* h_enc = (float*)(ws + WS_HENC);
  float* c_enc = (float*)(ws + WS_CENC);

  // zero handshake state every launch (graph node -> deterministic replays)
  (void)hipMemsetAsync(ws, 0, WS_ZEND, stream);
  // allow >64KB dynamic LDS (gfx950 has 160KB/CU); idempotent host-side call
  (void)hipFuncSetAttribute((const void*)dec_kernel, hipFuncAttributeMaxDynamicSharedMemorySize, DYN_LDS);

  enc_kernel<<<NCELL, 512, 0, stream>>>(x, embed, eWih, eWhh, eb, h_enc, c_enc);
  dec_kernel<<<NWG, 512, DYN_LDS, stream>>>(embed, dWih, dWhh, db, fcw, fcb,
                                            h_enc, c_enc, h_dec, gbest, hcnt, mcnt, out);
}

// Round 6
// 6264.047 us; speedup vs baseline: 2.4689x; 2.0571x over previous
//
#include <hip/hip_runtime.h>
#include <math.h>

#define BB_ 32
#define TT_ 128
#define EE_ 64
#define HH_ 128
#define VV_ 32000
#define NMM 200      // matmul workgroups
#define NCELL 32     // cell workgroups (one per batch)
#define NWG (NMM + NCELL)
#define VW 160       // vocab rows per matmul wg (200*160 = 32000)

// ---- dynamic LDS layout (bytes) for matmul wgs ----
#define OFF_LW  0                   // float4[32 kcc][160 r] = 81920  fc_w slice
#define OFF_LHB 81920               // float[32 b][128 k]    = 16384  h tile
#define OFF_RDF 98304               // float[3*128 slots]*41 = 62976  k-split reduce (stride 41: conflict-free)
// cell wgs overlay (same dynamic buffer, different CUs)
#define OFF_SG  0                   // float[512] gates
#define OFF_SH  2048                // float[128] h
#define OFF_TOK 2560                // int token broadcast
#define DYN_LDS 161280              // 157.5KB -> 1 wg/CU (160KB pool)

// ---- workspace layout (bytes) ----
#define WS_GBEST 0                  // u64[129*32] = 33024  per-(step,batch) argmax (packed)
#define WS_HCNT  33024              // u32[160] = 640       cells done with step s
#define WS_MCNT  33664              // u32[160] = 640       matmuls done with step s
#define WS_ZEND  34304              // zero [0, WS_ZEND) each launch
#define WS_HDEC  34304              // float[32*128]
#define WS_HENC  50688              // float[32*128]
#define WS_CENC  67072              // float[32*128]
#define WS_END   83456

__device__ __forceinline__ float rlane(float v, int l){
  return __int_as_float(__builtin_amdgcn_readlane(__float_as_int(v), l));
}
__device__ __forceinline__ float sigm(float x){ return 1.f / (1.f + expf(-x)); }

__device__ __forceinline__ unsigned long long packmax(float v, int idx){
  unsigned u = __float_as_uint(v);
  u = (u & 0x80000000u) ? ~u : (u | 0x80000000u);   // monotone float->uint map
  return ((unsigned long long)u << 32) | (unsigned long long)(0xFFFFFFFFu - (unsigned)idx);
}

// RELAXED poll (no per-iteration L2 invalidate!) + single acquire fence on exit.
template <int SLP>
__device__ __forceinline__ void wait_eq(const unsigned* p, unsigned v){
  while (__hip_atomic_load(p, __ATOMIC_RELAXED, __HIP_MEMORY_SCOPE_AGENT) != v)
    __builtin_amdgcn_s_sleep(SLP);
  __builtin_amdgcn_fence(__ATOMIC_ACQUIRE, "agent");
}

// gate[row=t] = bias + sum_e wih[e]*x[e] + sum_j whh[j]*h[j]; x/h broadcast via readlane
__device__ __forceinline__ float gate_dot(const float (&wih)[EE_], const float (&whh)[HH_],
                                          float bias, float xe, float h0, float h1){
  float a0 = bias, a1 = 0.f, a2 = 0.f, a3 = 0.f;
#pragma unroll
  for (int e = 0; e < EE_; e += 4){
    a0 = fmaf(wih[e+0], rlane(xe, e+0), a0);
    a1 = fmaf(wih[e+1], rlane(xe, e+1), a1);
    a2 = fmaf(wih[e+2], rlane(xe, e+2), a2);
    a3 = fmaf(wih[e+3], rlane(xe, e+3), a3);
  }
#pragma unroll
  for (int j = 0; j < 64; j += 4){
    a0 = fmaf(whh[j+0], rlane(h0, j+0), a0);
    a1 = fmaf(whh[j+1], rlane(h0, j+1), a1);
    a2 = fmaf(whh[j+2], rlane(h0, j+2), a2);
    a3 = fmaf(whh[j+3], rlane(h0, j+3), a3);
  }
#pragma unroll
  for (int j = 0; j < 64; j += 4){
    a0 = fmaf(whh[64+j+0], rlane(h1, j+0), a0);
    a1 = fmaf(whh[64+j+1], rlane(h1, j+1), a1);
    a2 = fmaf(whh[64+j+2], rlane(h1, j+2), a2);
    a3 = fmaf(whh[64+j+3], rlane(h1, j+3), a3);
  }
  return (a0 + a1) + (a2 + a3);
}

// ===================== encoder: 32 wgs (one per batch), no cross-wg deps =====================
__global__ __launch_bounds__(512)
void enc_kernel(const int* __restrict__ xt, const float* __restrict__ embed,
                const float* __restrict__ Wih, const float* __restrict__ Whh,
                const float* __restrict__ bv,
                float* __restrict__ h_out, float* __restrict__ c_out)
{
  const int b = blockIdx.x, t = threadIdx.x, lane = t & 63;
  __shared__ float sh[HH_];
  __shared__ float sg[4*HH_];
  float wih[EE_], whh[HH_];
#pragma unroll
  for (int e = 0; e < EE_; ++e) wih[e] = Wih[t*EE_ + e];
#pragma unroll
  for (int j = 0; j < HH_; ++j) whh[j] = Whh[t*HH_ + j];
  const float bias = bv[t];
  float c = 0.f, hv = 0.f;
  if (t < HH_) sh[t] = 0.f;
  __syncthreads();
#pragma unroll 1
  for (int s = 0; s < TT_; ++s){
    const int tok = xt[b*TT_ + s];
    const float xe = embed[tok*EE_ + lane];
    const float h0 = sh[lane], h1 = sh[64 + lane];
    const float g = gate_dot(wih, whh, bias, xe, h0, h1);
    __syncthreads();   // sh reads done before writes below
    sg[t] = g;
    __syncthreads();
    if (t < HH_){
      const float gi = sg[t], gf = sg[128+t], gg = sg[256+t], go = sg[384+t];
      c = sigm(gf)*c + sigm(gi)*tanhf(gg);
      hv = sigm(go)*tanhf(c);
      sh[t] = hv;
    }
    __syncthreads();
  }
  if (t < HH_){ h_out[b*HH_ + t] = hv; c_out[b*HH_ + t] = c; }
}

// ===================== decoder: persistent, 32 cell wgs + 200 matmul wgs =====================
__global__ __launch_bounds__(512)
void dec_kernel(const float* __restrict__ embed,
                const float* __restrict__ dWih, const float* __restrict__ dWhh,
                const float* __restrict__ db,
                const float* __restrict__ fcw, const float* __restrict__ fcb,
                const float* __restrict__ h_enc, const float* __restrict__ c_enc,
                float* __restrict__ h_dec, unsigned long long* __restrict__ gbest,
                unsigned* __restrict__ hcnt, unsigned* __restrict__ mcnt,
                float* __restrict__ out)
{
  extern __shared__ char smem[];
  const int t = threadIdx.x;
  const int wg = blockIdx.x;

  if (wg < NCELL){
    // ---------------- cell workgroup: owns batch b ----------------
    float* sg = (float*)(smem + OFF_SG);
    float* sh = (float*)(smem + OFF_SH);
    int* stok = (int*)(smem + OFF_TOK);
    const int b = wg, lane = t & 63;
    float wih[EE_], whh[HH_];
#pragma unroll
    for (int e = 0; e < EE_; ++e) wih[e] = dWih[t*EE_ + e];
#pragma unroll
    for (int j = 0; j < HH_; ++j) whh[j] = dWhh[t*HH_ + j];
    const float bias = db[t];
    float c = 0.f;
    if (t < HH_){ c = c_enc[b*HH_ + t]; sh[t] = h_enc[b*HH_ + t]; }
    int tok = 1; // SOS
    __syncthreads();
#pragma unroll 1
    for (int s = 1; s <= TT_; ++s){
      const float xe = embed[tok*EE_ + lane];
      const float h0 = sh[lane], h1 = sh[64 + lane];
      const float g = gate_dot(wih, whh, bias, xe, h0, h1);
      sg[t] = g;
      __syncthreads();
      if (t < HH_){
        const float gi = sg[t], gf = sg[128+t], gg = sg[256+t], go = sg[384+t];
        c = sigm(gf)*c + sigm(gi)*tanhf(gg);
        const float hv = sigm(go)*tanhf(c);
        sh[t] = hv;
        __hip_atomic_store(&h_dec[b*HH_ + t], hv, __ATOMIC_RELAXED, __HIP_MEMORY_SCOPE_AGENT);
      }
      __syncthreads();          // barrier drains vmem (compiler emits vmcnt(0) before s_barrier)
      if (t == 0){
        // RELEASE add: orders the h stores above before the count becomes visible
        __hip_atomic_fetch_add(&hcnt[s], 1u, __ATOMIC_RELEASE, __HIP_MEMORY_SCOPE_AGENT);
        wait_eq<1>(&mcnt[s], (unsigned)NMM);
        const unsigned long long gbv =
            __hip_atomic_load(&gbest[(size_t)s*BB_ + b], __ATOMIC_RELAXED, __HIP_MEMORY_SCOPE_AGENT);
        *stok = (int)(0xFFFFFFFFu - (unsigned)(gbv & 0xFFFFFFFFull));
      }
      __syncthreads();
      tok = *stok;
    }
  } else {
    // ---------------- matmul workgroup: vocab rows [v0, v0+VW) ----------------
    const int widx = wg - NCELL;
    const int v0 = widx * VW;
    float4* lw4 = (float4*)(smem + OFF_LW);   // [kcc][r]
    float*  lhb = (float*)(smem + OFF_LHB);   // [b][k], stride 128
    float*  rdf = (float*)(smem + OFF_RDF);
    const int ks = t >> 7;          // k-split quarter: k in [ks*32, ks*32+32)
    const int u  = t & 127;
    const int vg = u & 31;          // vocab lane; row v = v0 + vi*32 + vg
    const int bg = u >> 5;          // batch group (8 batches each)
    // stage fc_w slice into LDS once (reused for all 128 steps)
    for (int i = t; i < VW*HH_; i += 512){
      const int r = i >> 7, k = i & 127;
      ((float*)lw4)[((k >> 2)*VW + r)*4 + (k & 3)] = fcw[(size_t)(v0 + r)*HH_ + k];
    }
    float fb[5];
#pragma unroll
    for (int vi = 0; vi < 5; ++vi) fb[vi] = fcb[v0 + vi*32 + vg];
    const unsigned long long* hd64 = (const unsigned long long*)h_dec;
    __syncthreads();
#pragma unroll 1
    for (int s = 1; s <= TT_; ++s){
      if (t == 0) wait_eq<1>(&hcnt[s], (unsigned)NCELL);
      __syncthreads();
      // stage h into LDS [b][k] (agent-scope loads read the coherence point)
#pragma unroll
      for (int i = t; i < BB_*HH_/2; i += 512){
        const unsigned long long v =
            __hip_atomic_load(hd64 + i, __ATOMIC_RELAXED, __HIP_MEMORY_SCOPE_AGENT);
        const int bb = i >> 6, k2 = (i & 63)*2;
        float2 f;
        f.x = __uint_as_float((unsigned)(v & 0xFFFFFFFFull));
        f.y = __uint_as_float((unsigned)(v >> 32));
        *(float2*)&lhb[bb*HH_ + k2] = f;
      }
      __syncthreads();
      float acc[5][8];
#pragma unroll
      for (int vi = 0; vi < 5; ++vi)
#pragma unroll
        for (int bi = 0; bi < 8; ++bi) acc[vi][bi] = 0.f;
      const int kb = ks * 8;      // 8 float4-chunks (32 k) per ks
#pragma unroll
      for (int kc = 0; kc < 8; ++kc){
        const int kcc = kb + kc;
        float4 w[5];
#pragma unroll
        for (int vi = 0; vi < 5; ++vi) w[vi] = lw4[kcc*VW + vi*32 + vg];  // read ONCE per kc
#pragma unroll
        for (int bi = 0; bi < 8; ++bi){
          const float4 hb = *(const float4*)&lhb[(bg*8 + bi)*HH_ + kcc*4];  // broadcast read
#pragma unroll
          for (int vi = 0; vi < 5; ++vi)
            acc[vi][bi] = fmaf(w[vi].x,hb.x,fmaf(w[vi].y,hb.y,fmaf(w[vi].z,hb.z,fmaf(w[vi].w,hb.w,acc[vi][bi]))));
        }
      }
      // k-split reduce: ks=1..3 publish, ks=0 combines (stride-41 dwords: <=2-way banks)
      if (ks){
        float* dst = rdf + ((size_t)(ks-1)*128 + u)*41;
#pragma unroll
        for (int vi = 0; vi < 5; ++vi)
#pragma unroll
          for (int bi = 0; bi < 8; ++bi) dst[vi*8 + bi] = acc[vi][bi];
      }
      __syncthreads();
      if (ks == 0){
#pragma unroll
        for (int r = 0; r < 3; ++r){
          const float* src = rdf + ((size_t)r*128 + u)*41;
#pragma unroll
          for (int vi = 0; vi < 5; ++vi)
#pragma unroll
            for (int bi = 0; bi < 8; ++bi) acc[vi][bi] += src[vi*8 + bi];
        }
#pragma unroll
        for (int vi = 0; vi < 5; ++vi)
#pragma unroll
          for (int bi = 0; bi < 8; ++bi) acc[vi][bi] += fb[vi];
        // per-batch argmax over this wg's 160 rows: 5 local + butterfly over 32 vocab lanes
#pragma unroll
        for (int bi = 0; bi < 8; ++bi){
          unsigned long long best = 0ull;
#pragma unroll
          for (int vi = 0; vi < 5; ++vi){
            const unsigned long long pk = packmax(acc[vi][bi], v0 + vi*32 + vg);
            if (pk > best) best = pk;
          }
#pragma unroll
          for (int off = 16; off > 0; off >>= 1){
            const unsigned long long o = __shfl_xor(best, off);
            if (o > best) best = o;
          }
          if (vg == 0)
            __hip_atomic_fetch_max(&gbest[(size_t)s*BB_ + bg*8 + bi], best,
                                   __ATOMIC_RELAXED, __HIP_MEMORY_SCOPE_AGENT);
        }
      }
      __syncthreads();            // all waves' atomicMax issued (vmcnt drained at barrier)
      if (t == 0)
        __hip_atomic_fetch_add(&mcnt[s], 1u, __ATOMIC_RELEASE, __HIP_MEMORY_SCOPE_AGENT);
      // logits written AFTER the handshake (nontemporal: keep L2 for coherence traffic)
      if (ks == 0){
#pragma unroll
        for (int bi = 0; bi < 8; ++bi){
          float* orow = out + ((size_t)(bg*8 + bi)*TT_ + (s-1))*(size_t)VV_ + v0;
#pragma unroll
          for (int vi = 0; vi < 5; ++vi)
            __builtin_nontemporal_store(acc[vi][bi], &orow[vi*32 + vg]);
        }
      }
    }
  }
}

extern "C" void kernel_launch(void* const* d_in, const int* in_sizes, int n_in,
                              void* d_out, int out_size, void* d_ws, size_t ws_size,
                              hipStream_t stream){
  (void)in_sizes; (void)n_in; (void)out_size; (void)ws_size;
  const int*   x     = (const int*)  d_in[0];
  const float* embed = (const float*)d_in[1];
  const float* eWih  = (const float*)d_in[2];
  const float* eWhh  = (const float*)d_in[3];
  const float* eb    = (const float*)d_in[4];
  const float* dWih  = (const float*)d_in[5];
  const float* dWhh  = (const float*)d_in[6];
  const float* db    = (const float*)d_in[7];
  const float* fcw   = (const float*)d_in[8];
  const float* fcb   = (const float*)d_in[9];
  float* out = (float*)d_out;
  char* ws = (char*)d_ws;
  unsigned long long* gbest = (unsigned long long*)(ws + WS_GBEST);
  unsigned* hcnt = (unsigned*)(ws + WS_HCNT);
  unsigned* mcnt = (unsigned*)(ws + WS_MCNT);
  float* h_dec = (float*)(ws + WS_HDEC);
  float* h_enc = (float*)(ws + WS_HENC);
  float* c_enc = (float*)(ws + WS_CENC);

  // zero handshake state every launch (graph node -> deterministic replays)
  (void)hipMemsetAsync(ws, 0, WS_ZEND, stream);
  // allow >64KB dynamic LDS (gfx950 has 160KB/CU); idempotent host-side call
  (void)hipFuncSetAttribute((const void*)dec_kernel, hipFuncAttributeMaxDynamicSharedMemorySize, DYN_LDS);

  enc_kernel<<<NCELL, 512, 0, stream>>>(x, embed, eWih, eWhh, eb, h_enc, c_enc);
  dec_kernel<<<NWG, 512, DYN_LDS, stream>>>(embed, dWih, dWhh, db, fcw, fcb,
                                            h_enc, c_enc, h_dec, gbest, hcnt, mcnt, out);
}

// Round 7
// 5622.265 us; speedup vs baseline: 2.7507x; 1.1142x over previous
//
#include <hip/hip_runtime.h>
#include <math.h>

#define BB_ 32
#define TT_ 128
#define EE_ 64
#define HH_ 128
#define VV_ 32000
#define NMM 200      // matmul workgroups
#define NCELL 32     // cell workgroups (one per batch)
#define NWG (NMM + NCELL)
#define VW 160       // vocab rows per matmul wg (200*160 = 32000)

// ---- dynamic LDS layout (bytes) for matmul wgs ----
#define OFF_LW  0                   // float4[32 kcc][160 r] = 81920  fc_w slice
#define OFF_LHB 81920               // float[32 b][128 k]    = 16384  h tile
#define OFF_RDF 98304               // float[3*128]*41dw     = 62976  k-split reduce
// cell wgs overlay (same dynamic buffer, different CUs)
#define OFF_SG  0                   // float[512] gates
#define OFF_SH  2048                // float[128] h
#define OFF_TOK 2560                // int token broadcast
#define OFF_R64 2568                // u64[8] wave argmax partials
#define DYN_LDS 161280              // 157.5KB -> 1 wg/CU (160KB pool)

// ---- workspace layout (bytes) ----
#define WS_PART  0                  // u64[200*32] = 51200  per-(wg,batch) argmax partials
#define WS_HCNT  51200              // u32[136]             cells done with step s
#define WS_MCNT  51744              // u32[129*8] = 4128    matmuls done (8-way split)
#define WS_ZEND  55872              // zero [WS_HCNT, WS_ZEND) each launch
#define WS_HDEC  55872              // float[32*128]
#define WS_HENC  72256              // float[32*128]
#define WS_CENC  88640              // float[32*128]
#define WS_END   105024

__device__ __forceinline__ float rlane(float v, int l){
  return __int_as_float(__builtin_amdgcn_readlane(__float_as_int(v), l));
}
__device__ __forceinline__ float sigm(float x){ return 1.f / (1.f + expf(-x)); }

__device__ __forceinline__ unsigned long long packmax(float v, int idx){
  unsigned u = __float_as_uint(v);
  u = (u & 0x80000000u) ? ~u : (u | 0x80000000u);   // monotone float->uint map
  return ((unsigned long long)u << 32) | (unsigned long long)(0xFFFFFFFFu - (unsigned)idx);
}

// all cross-wg data moves via agent-scope ATOMIC ld/st (LLC-coherent, L2-bypassing),
// so flags need NO release/acquire cache maintenance: relaxed everywhere,
// workgroup-scope fence only for compiler ordering.
__device__ __forceinline__ unsigned aload(const unsigned* p){
  return __hip_atomic_load(p, __ATOMIC_RELAXED, __HIP_MEMORY_SCOPE_AGENT);
}
__device__ __forceinline__ unsigned long long aload64(const unsigned long long* p){
  return __hip_atomic_load(p, __ATOMIC_RELAXED, __HIP_MEMORY_SCOPE_AGENT);
}
__device__ __forceinline__ void wgfence(){
  __builtin_amdgcn_fence(__ATOMIC_ACQUIRE, "workgroup");
}

// gate[row] = bias + Whh[row,:]·h + Wih[row,:]·x ; weights streamed as float4 from
// global (L2-hot: 393KB/wg re-read each step), x/h broadcast via readlane.
// h-part first so the x-embedding load latency hides under it.
__device__ __forceinline__ float gate_dot_g(const float4* __restrict__ wih4,
                                            const float4* __restrict__ whh4,
                                            float bias, float xe, float h0, float h1){
  float a0 = bias, a1 = 0.f, a2 = 0.f, a3 = 0.f;
#pragma unroll
  for (int q = 0; q < 16; ++q){
    const float4 w = whh4[q];
    a0 = fmaf(w.x, rlane(h0, q*4+0), a0);
    a1 = fmaf(w.y, rlane(h0, q*4+1), a1);
    a2 = fmaf(w.z, rlane(h0, q*4+2), a2);
    a3 = fmaf(w.w, rlane(h0, q*4+3), a3);
  }
#pragma unroll
  for (int q = 0; q < 16; ++q){
    const float4 w = whh4[16+q];
    a0 = fmaf(w.x, rlane(h1, q*4+0), a0);
    a1 = fmaf(w.y, rlane(h1, q*4+1), a1);
    a2 = fmaf(w.z, rlane(h1, q*4+2), a2);
    a3 = fmaf(w.w, rlane(h1, q*4+3), a3);
  }
#pragma unroll
  for (int q = 0; q < 16; ++q){
    const float4 w = wih4[q];
    a0 = fmaf(w.x, rlane(xe, q*4+0), a0);
    a1 = fmaf(w.y, rlane(xe, q*4+1), a1);
    a2 = fmaf(w.z, rlane(xe, q*4+2), a2);
    a3 = fmaf(w.w, rlane(xe, q*4+3), a3);
  }
  return (a0 + a1) + (a2 + a3);
}

// ===================== encoder: 32 wgs (one per batch), no cross-wg deps =====================
__global__ __launch_bounds__(512)
void enc_kernel(const int* __restrict__ xt, const float* __restrict__ embed,
                const float* __restrict__ Wih, const float* __restrict__ Whh,
                const float* __restrict__ bv,
                float* __restrict__ h_out, float* __restrict__ c_out)
{
  const int b = blockIdx.x, t = threadIdx.x, lane = t & 63;
  __shared__ float sh[HH_];
  __shared__ float sg[4*HH_];
  const float bias = bv[t];
  float c = 0.f, hv = 0.f;
  if (t < HH_) sh[t] = 0.f;
  __syncthreads();
#pragma unroll 1
  for (int s = 0; s < TT_; ++s){
    const int tok = xt[b*TT_ + s];
    const float xe = embed[tok*EE_ + lane];
    const float h0 = sh[lane], h1 = sh[64 + lane];
    // opaque pointers: block LICM from hoisting 192 weight values out of the loop
    const float4* wp = (const float4*)(Wih + t*EE_);
    const float4* hp = (const float4*)(Whh + t*HH_);
    asm volatile("" : "+v"(wp), "+v"(hp));
    const float g = gate_dot_g(wp, hp, bias, xe, h0, h1);
    __syncthreads();   // all sh reads done
    sg[t] = g;
    __syncthreads();
    if (t < HH_){
      const float gi = sg[t], gf = sg[128+t], gg = sg[256+t], go = sg[384+t];
      c = sigm(gf)*c + sigm(gi)*tanhf(gg);
      hv = sigm(go)*tanhf(c);
      sh[t] = hv;
    }
    __syncthreads();
  }
  if (t < HH_){ h_out[b*HH_ + t] = hv; c_out[b*HH_ + t] = c; }
}

// ===================== decoder: persistent, 32 cell wgs + 200 matmul wgs =====================
__global__ __launch_bounds__(512)
void dec_kernel(const float* __restrict__ embed,
                const float* __restrict__ dWih, const float* __restrict__ dWhh,
                const float* __restrict__ db,
                const float* __restrict__ fcw, const float* __restrict__ fcb,
                const float* __restrict__ h_enc, const float* __restrict__ c_enc,
                float* __restrict__ h_dec, unsigned long long* __restrict__ part,
                unsigned* __restrict__ hcnt, unsigned* __restrict__ mcnt,
                float* __restrict__ out)
{
  extern __shared__ char smem[];
  const int t = threadIdx.x;
  const int wg = blockIdx.x;

  if (wg < NCELL){
    // ---------------- cell workgroup: owns batch b ----------------
    float* sg = (float*)(smem + OFF_SG);
    float* sh = (float*)(smem + OFF_SH);
    int* stok = (int*)(smem + OFF_TOK);
    unsigned long long* r64 = (unsigned long long*)(smem + OFF_R64);
    const int b = wg, lane = t & 63;
    const float bias = db[t];
    float c = 0.f;
    if (t < HH_){ c = c_enc[b*HH_ + t]; sh[t] = h_enc[b*HH_ + t]; }
    int tok = 1; // SOS
    __syncthreads();
#pragma unroll 1
    for (int s = 1; s <= TT_; ++s){
      const float xe = embed[tok*EE_ + lane];
      const float h0 = sh[lane], h1 = sh[64 + lane];
      const float4* wp = (const float4*)(dWih + t*EE_);
      const float4* hp = (const float4*)(dWhh + t*HH_);
      asm volatile("" : "+v"(wp), "+v"(hp));
      const float g = gate_dot_g(wp, hp, bias, xe, h0, h1);
      sg[t] = g;
      __syncthreads();
      if (t < HH_){
        const float gi = sg[t], gf = sg[128+t], gg = sg[256+t], go = sg[384+t];
        c = sigm(gf)*c + sigm(gi)*tanhf(gg);
        const float hv = sigm(go)*tanhf(c);
        sh[t] = hv;
        __hip_atomic_store(&h_dec[b*HH_ + t], hv, __ATOMIC_RELAXED, __HIP_MEMORY_SCOPE_AGENT);
      }
      __syncthreads();          // barrier drains the atomic h stores (vmcnt0 before s_barrier)
      if (t == 0){
        __hip_atomic_fetch_add(&hcnt[s], 1u, __ATOMIC_RELAXED, __HIP_MEMORY_SCOPE_AGENT);
        // poll 8-way-split matmul counters
        const unsigned* mc = &mcnt[(size_t)s*8];
        for (;;){
          unsigned sum = 0;
#pragma unroll
          for (int j = 0; j < 8; ++j) sum += aload(&mc[j]);
          if (sum == (unsigned)NMM) break;
          __builtin_amdgcn_s_sleep(1);
        }
      }
      __syncthreads();          // release the rest of the wg once t0 saw completion
      wgfence();
      // 200-wide argmax reduce over per-wg partials for this batch
      unsigned long long m = 0ull;
      if (t < NMM) m = aload64(&part[(size_t)t*BB_ + b]);
#pragma unroll
      for (int off = 32; off > 0; off >>= 1){
        const unsigned long long o = __shfl_xor(m, off);
        if (o > m) m = o;
      }
      if ((t & 63) == 0) r64[t >> 6] = m;
      __syncthreads();
      if (t == 0){
        unsigned long long best = r64[0];
#pragma unroll
        for (int w = 1; w < 8; ++w) if (r64[w] > best) best = r64[w];
        *stok = (int)(0xFFFFFFFFu - (unsigned)(best & 0xFFFFFFFFull));
      }
      __syncthreads();
      tok = *stok;
    }
  } else {
    // ---------------- matmul workgroup: vocab rows [v0, v0+VW) ----------------
    const int widx = wg - NCELL;
    const int v0 = widx * VW;
    float4* lw4 = (float4*)(smem + OFF_LW);   // [kcc][r]
    float*  lhb = (float*)(smem + OFF_LHB);   // [b][k], stride 128
    float*  rdf = (float*)(smem + OFF_RDF);
    const int ks = t >> 7;          // k-split quarter: k in [ks*32, ks*32+32)
    const int u  = t & 127;
    const int vg = u & 31;          // vocab lane; row v = v0 + vi*32 + vg
    const int bg = u >> 5;          // batch group (8 batches each)
    // stage fc_w slice into LDS once (reused for all 128 steps)
    for (int i = t; i < VW*HH_; i += 512){
      const int r = i >> 7, k = i & 127;
      ((float*)lw4)[((k >> 2)*VW + r)*4 + (k & 3)] = fcw[(size_t)(v0 + r)*HH_ + k];
    }
    float fb[5];
#pragma unroll
    for (int vi = 0; vi < 5; ++vi) fb[vi] = fcb[v0 + vi*32 + vg];
    const unsigned long long* hd64 = (const unsigned long long*)h_dec;
    __syncthreads();
#pragma unroll 1
    for (int s = 1; s <= TT_; ++s){
      if (t == 0){
        while (aload(&hcnt[s]) != (unsigned)NCELL) __builtin_amdgcn_s_sleep(1);
      }
      __syncthreads();
      wgfence();
      // stage h into LDS [b][k] (atomic loads are LLC-coherent; no cache inv needed)
#pragma unroll
      for (int i = t; i < BB_*HH_/2; i += 512){
        const unsigned long long v = aload64(hd64 + i);
        const int bb = i >> 6, k2 = (i & 63)*2;
        float2 f;
        f.x = __uint_as_float((unsigned)(v & 0xFFFFFFFFull));
        f.y = __uint_as_float((unsigned)(v >> 32));
        *(float2*)&lhb[bb*HH_ + k2] = f;
      }
      __syncthreads();
      float acc[5][8];
#pragma unroll
      for (int vi = 0; vi < 5; ++vi)
#pragma unroll
        for (int bi = 0; bi < 8; ++bi) acc[vi][bi] = 0.f;
      const int kb = ks * 8;      // 8 float4-chunks (32 k) per ks
#pragma unroll
      for (int kc = 0; kc < 8; ++kc){
        const int kcc = kb + kc;
        float4 w[5];
#pragma unroll
        for (int vi = 0; vi < 5; ++vi) w[vi] = lw4[kcc*VW + vi*32 + vg];  // read ONCE per kc
#pragma unroll
        for (int bi = 0; bi < 8; ++bi){
          const float4 hb = *(const float4*)&lhb[(bg*8 + bi)*HH_ + kcc*4];  // broadcast read
#pragma unroll
          for (int vi = 0; vi < 5; ++vi)
            acc[vi][bi] = fmaf(w[vi].x,hb.x,fmaf(w[vi].y,hb.y,fmaf(w[vi].z,hb.z,fmaf(w[vi].w,hb.w,acc[vi][bi]))));
        }
      }
      // k-split reduce: ks=1..3 publish, ks=0 combines (stride-41 dwords: <=2-way banks)
      if (ks){
        float* dst = rdf + ((size_t)(ks-1)*128 + u)*41;
#pragma unroll
        for (int vi = 0; vi < 5; ++vi)
#pragma unroll
          for (int bi = 0; bi < 8; ++bi) dst[vi*8 + bi] = acc[vi][bi];
      }
      __syncthreads();
      if (ks == 0){
#pragma unroll
        for (int r = 0; r < 3; ++r){
          const float* src = rdf + ((size_t)r*128 + u)*41;
#pragma unroll
          for (int vi = 0; vi < 5; ++vi)
#pragma unroll
            for (int bi = 0; bi < 8; ++bi) acc[vi][bi] += src[vi*8 + bi];
        }
#pragma unroll
        for (int vi = 0; vi < 5; ++vi)
#pragma unroll
          for (int bi = 0; bi < 8; ++bi) acc[vi][bi] += fb[vi];
        // per-batch argmax over this wg's 160 rows -> ONE uncontended store per (wg,batch)
#pragma unroll
        for (int bi = 0; bi < 8; ++bi){
          unsigned long long best = 0ull;
#pragma unroll
          for (int vi = 0; vi < 5; ++vi){
            const unsigned long long pk = packmax(acc[vi][bi], v0 + vi*32 + vg);
            if (pk > best) best = pk;
          }
#pragma unroll
          for (int off = 16; off > 0; off >>= 1){
            const unsigned long long o = __shfl_xor(best, off);
            if (o > best) best = o;
          }
          if (vg == 0)
            __hip_atomic_store(&part[(size_t)widx*BB_ + bg*8 + bi], best,
                               __ATOMIC_RELAXED, __HIP_MEMORY_SCOPE_AGENT);
        }
      }
      __syncthreads();            // drain part stores (vmcnt0 before s_barrier)
      if (t == 0)
        __hip_atomic_fetch_add(&mcnt[(size_t)s*8 + (widx & 7)], 1u,
                               __ATOMIC_RELAXED, __HIP_MEMORY_SCOPE_AGENT);
      // logits written AFTER the handshake (nontemporal; drain in next step's shadow)
      if (ks == 0){
#pragma unroll
        for (int bi = 0; bi < 8; ++bi){
          float* orow = out + ((size_t)(bg*8 + bi)*TT_ + (s-1))*(size_t)VV_ + v0;
#pragma unroll
          for (int vi = 0; vi < 5; ++vi)
            __builtin_nontemporal_store(acc[vi][bi], &orow[vi*32 + vg]);
        }
      }
    }
  }
}

extern "C" void kernel_launch(void* const* d_in, const int* in_sizes, int n_in,
                              void* d_out, int out_size, void* d_ws, size_t ws_size,
                              hipStream_t stream){
  (void)in_sizes; (void)n_in; (void)out_size; (void)ws_size;
  const int*   x     = (const int*)  d_in[0];
  const float* embed = (const float*)d_in[1];
  const float* eWih  = (const float*)d_in[2];
  const float* eWhh  = (const float*)d_in[3];
  const float* eb    = (const float*)d_in[4];
  const float* dWih  = (const float*)d_in[5];
  const float* dWhh  = (const float*)d_in[6];
  const float* db    = (const float*)d_in[7];
  const float* fcw   = (const float*)d_in[8];
  const float* fcb   = (const float*)d_in[9];
  float* out = (float*)d_out;
  char* ws = (char*)d_ws;
  unsigned long long* part = (unsigned long long*)(ws + WS_PART);
  unsigned* hcnt = (unsigned*)(ws + WS_HCNT);
  unsigned* mcnt = (unsigned*)(ws + WS_MCNT);
  float* h_dec = (float*)(ws + WS_HDEC);
  float* h_enc = (float*)(ws + WS_HENC);
  float* c_enc = (float*)(ws + WS_CENC);

  // zero handshake counters every launch (graph node -> deterministic replays)
  (void)hipMemsetAsync(ws + WS_HCNT, 0, WS_ZEND - WS_HCNT, stream);
  // allow >64KB dynamic LDS (gfx950 has 160KB/CU); idempotent host-side call
  (void)hipFuncSetAttribute((const void*)dec_kernel, hipFuncAttributeMaxDynamicSharedMemorySize, DYN_LDS);

  enc_kernel<<<NCELL, 512, 0, stream>>>(x, embed, eWih, eWhh, eb, h_enc, c_enc);
  dec_kernel<<<NWG, 512, DYN_LDS, stream>>>(embed, dWih, dWhh, db, fcw, fcb,
                                            h_enc, c_enc, h_dec, part, hcnt, mcnt, out);
}

// Round 8
// 4527.055 us; speedup vs baseline: 3.4162x; 1.2419x over previous
//
#include <hip/hip_runtime.h>
#include <math.h>

#define BB_ 32
#define TT_ 128
#define EE_ 64
#define HH_ 128
#define VV_ 32000
#define NMM 200      // matmul workgroups
#define NCELL 32     // cell workgroups (one per batch)
#define NWG (NMM + NCELL)
#define VW 160       // vocab rows per matmul wg (200*160 = 32000)

// ---- dynamic LDS layout (bytes) for matmul wgs ----
#define OFF_LW  0                   // float4[32 kcc][160 r] = 81920  fc_w slice
#define OFF_LHB 81920               // float[32 b][128 k]    = 16384  h tile
#define OFF_RDF 98304               // float[3*128]*41dw     = 62976  k-split reduce
// cell wgs overlay (same dynamic buffer, different CUs)
#define OFF_SG  0                   // float[512] gates
#define OFF_SH  2048                // float[128] h
#define OFF_TOK 2560                // int token broadcast
#define OFF_R64 2568                // u64[8] wave argmax partials
#define DYN_LDS 161280              // 157.5KB -> 1 wg/CU (160KB pool)

// ---- workspace layout (bytes) ----
// per-step write-once buffers: writers use agent-atomic stores (-> LLC),
// readers use PLAIN cached loads (per-XCD L2 absorbs the 200-wg fan-out;
// fresh because lines are first-touched after the step flag and dispatch
// start performs the HSA acquire invalidate).
#define WS_PART  0                                  // u64[TT][NMM][BB] = 6,553,600
#define WS_HDEC  (TT_*NMM*BB_*8)                    // f32[TT][BB][HH]  = 2,097,152
#define WS_HREP  (WS_HDEC + TT_*BB_*HH_*4)          // u32[TT][8] h-ready replicas
#define WS_MCNT  (WS_HREP + TT_*8*4)                // u32[TT][8] matmul-done (8-way)
#define WS_ZEND  (WS_MCNT + TT_*8*4)
#define WS_HENC  WS_ZEND                            // f32[BB*HH]
#define WS_CENC  (WS_HENC + BB_*HH_*4)              // f32[BB*HH]
#define WS_END   (WS_CENC + BB_*HH_*4)

__device__ __forceinline__ float rlane(float v, int l){
  return __int_as_float(__builtin_amdgcn_readlane(__float_as_int(v), l));
}
__device__ __forceinline__ float sigm(float x){ return 1.f / (1.f + expf(-x)); }

__device__ __forceinline__ unsigned long long packmax(float v, int idx){
  unsigned u = __float_as_uint(v);
  u = (u & 0x80000000u) ? ~u : (u | 0x80000000u);   // monotone float->uint map
  return ((unsigned long long)u << 32) | (unsigned long long)(0xFFFFFFFFu - (unsigned)idx);
}

__device__ __forceinline__ unsigned aload(const unsigned* p){
  return __hip_atomic_load(p, __ATOMIC_RELAXED, __HIP_MEMORY_SCOPE_AGENT);
}

// gate[row] = bias + Whh[row,:]·h + Wih[row,:]·x ; weights streamed as float4
// (L2-hot), x/h broadcast via readlane. h-part first to hide the x load.
__device__ __forceinline__ float gate_dot_g(const float4* __restrict__ wih4,
                                            const float4* __restrict__ whh4,
                                            float bias, float xe, float h0, float h1){
  float a0 = bias, a1 = 0.f, a2 = 0.f, a3 = 0.f;
#pragma unroll
  for (int q = 0; q < 16; ++q){
    const float4 w = whh4[q];
    a0 = fmaf(w.x, rlane(h0, q*4+0), a0);
    a1 = fmaf(w.y, rlane(h0, q*4+1), a1);
    a2 = fmaf(w.z, rlane(h0, q*4+2), a2);
    a3 = fmaf(w.w, rlane(h0, q*4+3), a3);
  }
#pragma unroll
  for (int q = 0; q < 16; ++q){
    const float4 w = whh4[16+q];
    a0 = fmaf(w.x, rlane(h1, q*4+0), a0);
    a1 = fmaf(w.y, rlane(h1, q*4+1), a1);
    a2 = fmaf(w.z, rlane(h1, q*4+2), a2);
    a3 = fmaf(w.w, rlane(h1, q*4+3), a3);
  }
#pragma unroll
  for (int q = 0; q < 16; ++q){
    const float4 w = wih4[q];
    a0 = fmaf(w.x, rlane(xe, q*4+0), a0);
    a1 = fmaf(w.y, rlane(xe, q*4+1), a1);
    a2 = fmaf(w.z, rlane(xe, q*4+2), a2);
    a3 = fmaf(w.w, rlane(xe, q*4+3), a3);
  }
  return (a0 + a1) + (a2 + a3);
}

// dot with register-resident weights (encoder: no handshake, spill is L2-hot)
__device__ __forceinline__ float gate_dot_r(const float (&wih)[EE_], const float (&whh)[HH_],
                                            float bias, float xe, float h0, float h1){
  float a0 = bias, a1 = 0.f, a2 = 0.f, a3 = 0.f;
#pragma unroll
  for (int e = 0; e < EE_; e += 4){
    a0 = fmaf(wih[e+0], rlane(xe, e+0), a0);
    a1 = fmaf(wih[e+1], rlane(xe, e+1), a1);
    a2 = fmaf(wih[e+2], rlane(xe, e+2), a2);
    a3 = fmaf(wih[e+3], rlane(xe, e+3), a3);
  }
#pragma unroll
  for (int j = 0; j < 64; j += 4){
    a0 = fmaf(whh[j+0], rlane(h0, j+0), a0);
    a1 = fmaf(whh[j+1], rlane(h0, j+1), a1);
    a2 = fmaf(whh[j+2], rlane(h0, j+2), a2);
    a3 = fmaf(whh[j+3], rlane(h0, j+3), a3);
  }
#pragma unroll
  for (int j = 0; j < 64; j += 4){
    a0 = fmaf(whh[64+j+0], rlane(h1, j+0), a0);
    a1 = fmaf(whh[64+j+1], rlane(h1, j+1), a1);
    a2 = fmaf(whh[64+j+2], rlane(h1, j+2), a2);
    a3 = fmaf(whh[64+j+3], rlane(h1, j+3), a3);
  }
  return (a0 + a1) + (a2 + a3);
}

// ===================== encoder: 32 wgs (one per batch), no cross-wg deps =====================
__global__ __launch_bounds__(512)
void enc_kernel(const int* __restrict__ xt, const float* __restrict__ embed,
                const float* __restrict__ Wih, const float* __restrict__ Whh,
                const float* __restrict__ bv,
                float* __restrict__ h_out, float* __restrict__ c_out)
{
  const int b = blockIdx.x, t = threadIdx.x, lane = t & 63;
  __shared__ float sh[HH_];
  __shared__ float sg[4*HH_];
  float wih[EE_], whh[HH_];
#pragma unroll
  for (int e = 0; e < EE_; ++e) wih[e] = Wih[t*EE_ + e];
#pragma unroll
  for (int j = 0; j < HH_; ++j) whh[j] = Whh[t*HH_ + j];
  const float bias = bv[t];
  float c = 0.f, hv = 0.f;
  if (t < HH_) sh[t] = 0.f;
  __syncthreads();
#pragma unroll 1
  for (int s = 0; s < TT_; ++s){
    const int tok = xt[b*TT_ + s];
    const float xe = embed[tok*EE_ + lane];
    const float h0 = sh[lane], h1 = sh[64 + lane];
    const float g = gate_dot_r(wih, whh, bias, xe, h0, h1);
    __syncthreads();   // all sh reads done
    sg[t] = g;
    __syncthreads();
    if (t < HH_){
      const float gi = sg[t], gf = sg[128+t], gg = sg[256+t], go = sg[384+t];
      c = sigm(gf)*c + sigm(gi)*tanhf(gg);
      hv = sigm(go)*tanhf(c);
      sh[t] = hv;
    }
    __syncthreads();
  }
  if (t < HH_){ h_out[b*HH_ + t] = hv; c_out[b*HH_ + t] = c; }
}

// ===================== decoder: persistent, 32 cell wgs + 200 matmul wgs =====================
__global__ __launch_bounds__(512)
void dec_kernel(const float* __restrict__ embed,
                const float* __restrict__ dWih, const float* __restrict__ dWhh,
                const float* __restrict__ db,
                const float* __restrict__ fcw, const float* __restrict__ fcb,
                const float* __restrict__ h_enc, const float* __restrict__ c_enc,
                float* __restrict__ h_dec, unsigned long long* __restrict__ part,
                unsigned* __restrict__ hrep, unsigned* __restrict__ mcnt,
                float* __restrict__ out)
{
  extern __shared__ char smem[];
  const int t = threadIdx.x;
  const int wg = blockIdx.x;

  if (wg < NCELL){
    // ---------------- cell workgroup: owns batch b ----------------
    float* sg = (float*)(smem + OFF_SG);
    float* sh = (float*)(smem + OFF_SH);
    int* stok = (int*)(smem + OFF_TOK);
    unsigned long long* r64 = (unsigned long long*)(smem + OFF_R64);
    const int b = wg, lane = t & 63;
    const float bias = db[t];
    float c = 0.f;
    if (t < HH_){ c = c_enc[b*HH_ + t]; sh[t] = h_enc[b*HH_ + t]; }
    int tok = 1; // SOS
    __syncthreads();
#pragma unroll 1
    for (int s = 0; s < TT_; ++s){
      const float xe = embed[tok*EE_ + lane];
      const float h0 = sh[lane], h1 = sh[64 + lane];
      const float4* wp = (const float4*)(dWih + t*EE_);
      const float4* hp = (const float4*)(dWhh + t*HH_);
      asm volatile("" : "+v"(wp), "+v"(hp));   // block LICM (VGPR can't hold 192 w)
      const float g = gate_dot_g(wp, hp, bias, xe, h0, h1);
      sg[t] = g;
      __syncthreads();
      if (t < HH_){
        const float gi = sg[t], gf = sg[128+t], gg = sg[256+t], go = sg[384+t];
        c = sigm(gf)*c + sigm(gi)*tanhf(gg);
        const float hv = sigm(go)*tanhf(c);
        sh[t] = hv;
        __hip_atomic_store(&h_dec[(size_t)s*BB_*HH_ + b*HH_ + t], hv,
                           __ATOMIC_RELAXED, __HIP_MEMORY_SCOPE_AGENT);
      }
      __syncthreads();          // vmcnt(0): h stores complete at LLC
      if (t < 8)                // bump all 8 h-ready replicas in parallel
        __hip_atomic_fetch_add(&hrep[s*8 + t], 1u, __ATOMIC_RELAXED, __HIP_MEMORY_SCOPE_AGENT);
      if (t == 0){
        const unsigned* mc = &mcnt[s*8];
        for (;;){
          unsigned sum = 0;
#pragma unroll
          for (int j = 0; j < 8; ++j) sum += aload(&mc[j]);
          if (sum == (unsigned)NMM) break;
          __builtin_amdgcn_s_sleep(1);
        }
      }
      __syncthreads();
      // PLAIN cached gather of this step's argmax partials (write-once buffer)
      const unsigned long long* ps = part + (size_t)s*NMM*BB_;
      unsigned long long m = 0ull;
      if (t < NMM) m = ps[(size_t)t*BB_ + b];
#pragma unroll
      for (int off = 32; off > 0; off >>= 1){
        const unsigned long long o = __shfl_xor(m, off);
        if (o > m) m = o;
      }
      if ((t & 63) == 0) r64[t >> 6] = m;
      __syncthreads();
      if (t == 0){
        unsigned long long best = r64[0];
#pragma unroll
        for (int w = 1; w < 8; ++w) if (r64[w] > best) best = r64[w];
        *stok = (int)(0xFFFFFFFFu - (unsigned)(best & 0xFFFFFFFFull));
      }
      __syncthreads();
      tok = *stok;
    }
  } else {
    // ---------------- matmul workgroup: vocab rows [v0, v0+VW) ----------------
    const int widx = wg - NCELL;
    const int v0 = widx * VW;
    float4* lw4 = (float4*)(smem + OFF_LW);   // [kcc][r]
    float*  lhb = (float*)(smem + OFF_LHB);   // [b][k], stride 128
    float*  rdf = (float*)(smem + OFF_RDF);
    const int ks = t >> 7;          // k-split quarter: k in [ks*32, ks*32+32)
    const int u  = t & 127;
    const int vg = u & 31;          // vocab lane; row v = v0 + vi*32 + vg
    const int bg = u >> 5;          // batch group (8 batches each)
    // stage fc_w slice into LDS once (reused for all 128 steps)
    for (int i = t; i < VW*HH_; i += 512){
      const int r = i >> 7, k = i & 127;
      ((float*)lw4)[((k >> 2)*VW + r)*4 + (k & 3)] = fcw[(size_t)(v0 + r)*HH_ + k];
    }
    float fb[5];
#pragma unroll
    for (int vi = 0; vi < 5; ++vi) fb[vi] = fcb[v0 + vi*32 + vg];
    __syncthreads();
#pragma unroll 1
    for (int s = 0; s < TT_; ++s){
      if (t == 0){
        while (aload(&hrep[s*8 + (widx & 7)]) != (unsigned)NCELL)
          __builtin_amdgcn_s_sleep(1);
      }
      __syncthreads();
      // PLAIN cached, coalesced h load (per-step write-once buffer; L2 multicasts)
      const float4* hsrc = (const float4*)(h_dec + (size_t)s*BB_*HH_);
#pragma unroll
      for (int i = t; i < BB_*HH_/4; i += 512){
        const float4 v = hsrc[i];
        const int bb = i >> 5, k4 = i & 31;
        *(float4*)&lhb[bb*HH_ + k4*4] = v;
      }
      __syncthreads();
      float acc[5][8];
#pragma unroll
      for (int vi = 0; vi < 5; ++vi)
#pragma unroll
        for (int bi = 0; bi < 8; ++bi) acc[vi][bi] = 0.f;
      const int kb = ks * 8;      // 8 float4-chunks (32 k) per ks
#pragma unroll
      for (int kc = 0; kc < 8; ++kc){
        const int kcc = kb + kc;
        float4 w[5];
#pragma unroll
        for (int vi = 0; vi < 5; ++vi) w[vi] = lw4[kcc*VW + vi*32 + vg];  // read ONCE per kc
#pragma unroll
        for (int bi = 0; bi < 8; ++bi){
          const float4 hb = *(const float4*)&lhb[(bg*8 + bi)*HH_ + kcc*4];  // broadcast read
#pragma unroll
          for (int vi = 0; vi < 5; ++vi)
            acc[vi][bi] = fmaf(w[vi].x,hb.x,fmaf(w[vi].y,hb.y,fmaf(w[vi].z,hb.z,fmaf(w[vi].w,hb.w,acc[vi][bi]))));
        }
      }
      // k-split reduce: ks=1..3 publish, ks=0 combines (stride-41 dwords)
      if (ks){
        float* dst = rdf + ((size_t)(ks-1)*128 + u)*41;
#pragma unroll
        for (int vi = 0; vi < 5; ++vi)
#pragma unroll
          for (int bi = 0; bi < 8; ++bi) dst[vi*8 + bi] = acc[vi][bi];
      }
      __syncthreads();
      if (ks == 0){
#pragma unroll
        for (int r = 0; r < 3; ++r){
          const float* src = rdf + ((size_t)r*128 + u)*41;
#pragma unroll
          for (int vi = 0; vi < 5; ++vi)
#pragma unroll
            for (int bi = 0; bi < 8; ++bi) acc[vi][bi] += src[vi*8 + bi];
        }
#pragma unroll
        for (int vi = 0; vi < 5; ++vi)
#pragma unroll
          for (int bi = 0; bi < 8; ++bi) acc[vi][bi] += fb[vi];
        // per-batch argmax over this wg's 160 rows -> ONE atomic store per (wg,batch)
#pragma unroll
        for (int bi = 0; bi < 8; ++bi){
          unsigned long long best = 0ull;
#pragma unroll
          for (int vi = 0; vi < 5; ++vi){
            const unsigned long long pk = packmax(acc[vi][bi], v0 + vi*32 + vg);
            if (pk > best) best = pk;
          }
#pragma unroll
          for (int off = 16; off > 0; off >>= 1){
            const unsigned long long o = __shfl_xor(best, off);
            if (o > best) best = o;
          }
          if (vg == 0)
            __hip_atomic_store(&part[(size_t)s*NMM*BB_ + (size_t)widx*BB_ + bg*8 + bi], best,
                               __ATOMIC_RELAXED, __HIP_MEMORY_SCOPE_AGENT);
        }
      }
      __syncthreads();            // vmcnt(0): part stores complete at LLC
      if (t == 0)
        __hip_atomic_fetch_add(&mcnt[s*8 + (widx & 7)], 1u,
                               __ATOMIC_RELAXED, __HIP_MEMORY_SCOPE_AGENT);
      // logits written AFTER the handshake (nontemporal; drain in next step's shadow)
      if (ks == 0){
#pragma unroll
        for (int bi = 0; bi < 8; ++bi){
          float* orow = out + ((size_t)(bg*8 + bi)*TT_ + s)*(size_t)VV_ + v0;
#pragma unroll
          for (int vi = 0; vi < 5; ++vi)
            __builtin_nontemporal_store(acc[vi][bi], &orow[vi*32 + vg]);
        }
      }
    }
  }
}

extern "C" void kernel_launch(void* const* d_in, const int* in_sizes, int n_in,
                              void* d_out, int out_size, void* d_ws, size_t ws_size,
                              hipStream_t stream){
  (void)in_sizes; (void)n_in; (void)out_size; (void)ws_size;
  const int*   x     = (const int*)  d_in[0];
  const float* embed = (const float*)d_in[1];
  const float* eWih  = (const float*)d_in[2];
  const float* eWhh  = (const float*)d_in[3];
  const float* eb    = (const float*)d_in[4];
  const float* dWih  = (const float*)d_in[5];
  const float* dWhh  = (const float*)d_in[6];
  const float* db    = (const float*)d_in[7];
  const float* fcw   = (const float*)d_in[8];
  const float* fcb   = (const float*)d_in[9];
  float* out = (float*)d_out;
  char* ws = (char*)d_ws;
  unsigned long long* part = (unsigned long long*)(ws + WS_PART);
  float* h_dec = (float*)(ws + WS_HDEC);
  unsigned* hrep = (unsigned*)(ws + WS_HREP);
  unsigned* mcnt = (unsigned*)(ws + WS_MCNT);
  float* h_enc = (float*)(ws + WS_HENC);
  float* c_enc = (float*)(ws + WS_CENC);

  // zero handshake counters every launch (graph node -> deterministic replays)
  (void)hipMemsetAsync(ws + WS_HREP, 0, WS_ZEND - WS_HREP, stream);
  // allow >64KB dynamic LDS (gfx950 has 160KB/CU); idempotent host-side call
  (void)hipFuncSetAttribute((const void*)dec_kernel, hipFuncAttributeMaxDynamicSharedMemorySize, DYN_LDS);

  enc_kernel<<<NCELL, 512, 0, stream>>>(x, embed, eWih, eWhh, eb, h_enc, c_enc);
  dec_kernel<<<NWG, 512, DYN_LDS, stream>>>(embed, dWih, dWhh, db, fcw, fcb,
                                            h_enc, c_enc, h_dec, part, hrep, mcnt, out);
}

// Round 9
// 3413.805 us; speedup vs baseline: 4.5302x; 1.3261x over previous
//
#include <hip/hip_runtime.h>
#include <math.h>

#define BB_ 32
#define TT_ 128
#define EE_ 64
#define HH_ 128
#define VV_ 32000
#define NMM 200      // matmul workgroups
#define NCELL 32     // cell workgroups (one per batch)
#define NWG (NMM + NCELL)
#define VW 160       // vocab rows per matmul wg (200*160 = 32000)

// ---- dynamic LDS layout (bytes) for matmul wgs ----
#define OFF_LW  0                   // float4[32 kcc][160 r] = 81920  fc_w slice
#define OFF_LHB 81920               // float[32 b][128 k]    = 16384  h tile
#define OFF_RDF 98304               // float[3*128]*41dw     = 62976  k-split reduce
// cell wgs overlay (same dynamic buffer, different CUs)
#define OFF_SG  0                   // float[512] gates
#define OFF_SH  2048                // float[128] h
#define OFF_TOK 2560                // int token broadcast
#define OFF_R64 2568                // u64[8] wave argmax partials
#define DYN_LDS 161280              // 157.5KB -> 1 wg/CU (160KB pool)

// ---- workspace layout (bytes) ----
// NO flags, NO counters: data-sentinel handshakes only.
// hq[s][b][64]: u64 pairs of (h+2.0f) -- bits never zero since h+2 in (1,3).
// part[s][widx][b]: packmax values -- always nonzero by construction.
#define WS_HQ    0                                  // u64[TT][BB][64] = 2,097,152
#define WS_PART  (TT_*BB_*64*8)                     // u64[TT][NMM][BB] = 6,553,600
#define WS_ZEND  (WS_PART + (size_t)TT_*NMM*BB_*8) // zero [0, WS_ZEND) each launch
#define WS_HENC  WS_ZEND                            // f32[BB*HH]
#define WS_CENC  (WS_HENC + BB_*HH_*4)              // f32[BB*HH]
#define WS_END   (WS_CENC + BB_*HH_*4)

__device__ __forceinline__ float rlane(float v, int l){
  return __int_as_float(__builtin_amdgcn_readlane(__float_as_int(v), l));
}
__device__ __forceinline__ float sigm(float x){ return 1.f / (1.f + expf(-x)); }

__device__ __forceinline__ unsigned long long packmax(float v, int idx){
  unsigned u = __float_as_uint(v);
  u = (u & 0x80000000u) ? ~u : (u | 0x80000000u);   // monotone float->uint map
  return ((unsigned long long)u << 32) | (unsigned long long)(0xFFFFFFFFu - (unsigned)idx);
}

__device__ __forceinline__ unsigned long long aload64(const unsigned long long* p){
  return __hip_atomic_load(p, __ATOMIC_RELAXED, __HIP_MEMORY_SCOPE_AGENT);
}
__device__ __forceinline__ void astore64(unsigned long long* p, unsigned long long v){
  __hip_atomic_store(p, v, __ATOMIC_RELAXED, __HIP_MEMORY_SCOPE_AGENT);
}

// gate[row] = bias + Whh[row,:]·h + Wih[row,:]·x ; weights streamed as float4
// (L2-hot), x/h broadcast via readlane. h-part first to hide the x load.
__device__ __forceinline__ float gate_dot_g(const float4* __restrict__ wih4,
                                            const float4* __restrict__ whh4,
                                            float bias, float xe, float h0, float h1){
  float a0 = bias, a1 = 0.f, a2 = 0.f, a3 = 0.f;
#pragma unroll
  for (int q = 0; q < 16; ++q){
    const float4 w = whh4[q];
    a0 = fmaf(w.x, rlane(h0, q*4+0), a0);
    a1 = fmaf(w.y, rlane(h0, q*4+1), a1);
    a2 = fmaf(w.z, rlane(h0, q*4+2), a2);
    a3 = fmaf(w.w, rlane(h0, q*4+3), a3);
  }
#pragma unroll
  for (int q = 0; q < 16; ++q){
    const float4 w = whh4[16+q];
    a0 = fmaf(w.x, rlane(h1, q*4+0), a0);
    a1 = fmaf(w.y, rlane(h1, q*4+1), a1);
    a2 = fmaf(w.z, rlane(h1, q*4+2), a2);
    a3 = fmaf(w.w, rlane(h1, q*4+3), a3);
  }
#pragma unroll
  for (int q = 0; q < 16; ++q){
    const float4 w = wih4[q];
    a0 = fmaf(w.x, rlane(xe, q*4+0), a0);
    a1 = fmaf(w.y, rlane(xe, q*4+1), a1);
    a2 = fmaf(w.z, rlane(xe, q*4+2), a2);
    a3 = fmaf(w.w, rlane(xe, q*4+3), a3);
  }
  return (a0 + a1) + (a2 + a3);
}

// dot with register-resident weights (encoder only)
__device__ __forceinline__ float gate_dot_r(const float (&wih)[EE_], const float (&whh)[HH_],
                                            float bias, float xe, float h0, float h1){
  float a0 = bias, a1 = 0.f, a2 = 0.f, a3 = 0.f;
#pragma unroll
  for (int e = 0; e < EE_; e += 4){
    a0 = fmaf(wih[e+0], rlane(xe, e+0), a0);
    a1 = fmaf(wih[e+1], rlane(xe, e+1), a1);
    a2 = fmaf(wih[e+2], rlane(xe, e+2), a2);
    a3 = fmaf(wih[e+3], rlane(xe, e+3), a3);
  }
#pragma unroll
  for (int j = 0; j < 64; j += 4){
    a0 = fmaf(whh[j+0], rlane(h0, j+0), a0);
    a1 = fmaf(whh[j+1], rlane(h0, j+1), a1);
    a2 = fmaf(whh[j+2], rlane(h0, j+2), a2);
    a3 = fmaf(whh[j+3], rlane(h0, j+3), a3);
  }
#pragma unroll
  for (int j = 0; j < 64; j += 4){
    a0 = fmaf(whh[64+j+0], rlane(h1, j+0), a0);
    a1 = fmaf(whh[64+j+1], rlane(h1, j+1), a1);
    a2 = fmaf(whh[64+j+2], rlane(h1, j+2), a2);
    a3 = fmaf(whh[64+j+3], rlane(h1, j+3), a3);
  }
  return (a0 + a1) + (a2 + a3);
}

// ===================== encoder: 32 wgs (one per batch), no cross-wg deps =====================
__global__ __launch_bounds__(512)
void enc_kernel(const int* __restrict__ xt, const float* __restrict__ embed,
                const float* __restrict__ Wih, const float* __restrict__ Whh,
                const float* __restrict__ bv,
                float* __restrict__ h_out, float* __restrict__ c_out)
{
  const int b = blockIdx.x, t = threadIdx.x, lane = t & 63;
  __shared__ float sh[HH_];
  __shared__ float sg[4*HH_];
  float wih[EE_], whh[HH_];
#pragma unroll
  for (int e = 0; e < EE_; ++e) wih[e] = Wih[t*EE_ + e];
#pragma unroll
  for (int j = 0; j < HH_; ++j) whh[j] = Whh[t*HH_ + j];
  const float bias = bv[t];
  float c = 0.f, hv = 0.f;
  if (t < HH_) sh[t] = 0.f;
  __syncthreads();
#pragma unroll 1
  for (int s = 0; s < TT_; ++s){
    const int tok = xt[b*TT_ + s];
    const float xe = embed[tok*EE_ + lane];
    const float h0 = sh[lane], h1 = sh[64 + lane];
    const float g = gate_dot_r(wih, whh, bias, xe, h0, h1);
    __syncthreads();   // all sh reads done
    sg[t] = g;
    __syncthreads();
    if (t < HH_){
      const float gi = sg[t], gf = sg[128+t], gg = sg[256+t], go = sg[384+t];
      c = sigm(gf)*c + sigm(gi)*tanhf(gg);
      hv = sigm(go)*tanhf(c);
      sh[t] = hv;
    }
    __syncthreads();
  }
  if (t < HH_){ h_out[b*HH_ + t] = hv; c_out[b*HH_ + t] = c; }
}

// ===================== decoder: persistent, 32 cell wgs + 200 matmul wgs =====================
__global__ __launch_bounds__(512)
void dec_kernel(const float* __restrict__ embed,
                const float* __restrict__ dWih, const float* __restrict__ dWhh,
                const float* __restrict__ db,
                const float* __restrict__ fcw, const float* __restrict__ fcb,
                const float* __restrict__ h_enc, const float* __restrict__ c_enc,
                unsigned long long* __restrict__ hq, unsigned long long* __restrict__ part,
                float* __restrict__ out)
{
  extern __shared__ char smem[];
  const int t = threadIdx.x;
  const int wg = blockIdx.x;

  if (wg < NCELL){
    // ---------------- cell workgroup: owns batch b ----------------
    float* sg = (float*)(smem + OFF_SG);
    float* sh = (float*)(smem + OFF_SH);
    int* stok = (int*)(smem + OFF_TOK);
    unsigned long long* r64 = (unsigned long long*)(smem + OFF_R64);
    const int b = wg, lane = t & 63;
    const float bias = db[t];
    float c = 0.f;
    if (t < HH_){ c = c_enc[b*HH_ + t]; sh[t] = h_enc[b*HH_ + t]; }
    int tok = 1; // SOS
    __syncthreads();
#pragma unroll 1
    for (int s = 0; s < TT_; ++s){
      const float xe = embed[tok*EE_ + lane];
      const float h0 = sh[lane], h1 = sh[64 + lane];
      const float4* wp = (const float4*)(dWih + t*EE_);
      const float4* hp = (const float4*)(dWhh + t*HH_);
      asm volatile("" : "+v"(wp), "+v"(hp));   // block LICM (regs can't hold 192 w)
      const float g = gate_dot_g(wp, hp, bias, xe, h0, h1);
      sg[t] = g;
      __syncthreads();
      if (t < HH_){
        const float gi = sg[t], gf = sg[128+t], gg = sg[256+t], go = sg[384+t];
        c = sigm(gf)*c + sigm(gi)*tanhf(gg);
        const float hv = sigm(go)*tanhf(c);
        sh[t] = hv;
      }
      __syncthreads();           // sh complete
      // publish h as SENTINEL data: (h+2) in (1,3) -> bits never zero.
      if (t < 64){
        const unsigned lo = __float_as_uint(sh[2*t]   + 2.0f);
        const unsigned hi = __float_as_uint(sh[2*t+1] + 2.0f);
        astore64(&hq[((size_t)s*BB_ + b)*64 + t],
                 (unsigned long long)lo | ((unsigned long long)hi << 32));
      }
      // poll this batch's 200 argmax partials DIRECTLY (nonzero sentinel, no counter)
      unsigned long long m = 0ull;
      if (t < NMM){
        const unsigned long long* pp = part + ((size_t)s*NMM + t)*BB_ + b;
        while (!(m = aload64(pp))) __builtin_amdgcn_s_sleep(1);
      }
#pragma unroll
      for (int off = 32; off > 0; off >>= 1){
        const unsigned long long o = __shfl_xor(m, off);
        if (o > m) m = o;
      }
      if ((t & 63) == 0) r64[t >> 6] = m;
      __syncthreads();
      if (t == 0){
        unsigned long long best = r64[0];
#pragma unroll
        for (int w = 1; w < 8; ++w) if (r64[w] > best) best = r64[w];
        *stok = (int)(0xFFFFFFFFu - (unsigned)(best & 0xFFFFFFFFull));
      }
      __syncthreads();
      tok = *stok;
    }
  } else {
    // ---------------- matmul workgroup: vocab rows [v0, v0+VW) ----------------
    const int widx = wg - NCELL;
    const int v0 = widx * VW;
    float4* lw4 = (float4*)(smem + OFF_LW);   // [kcc][r]
    float*  lhb = (float*)(smem + OFF_LHB);   // [b][k], stride 128
    float*  rdf = (float*)(smem + OFF_RDF);
    const int ks = t >> 7;          // k-split quarter: k in [ks*32, ks*32+32)
    const int u  = t & 127;
    const int vg = u & 31;          // vocab lane; row v = v0 + vi*32 + vg
    const int bg = u >> 5;          // batch group (8 batches each)
    // stage fc_w slice into LDS once (reused for all 128 steps)
    for (int i = t; i < VW*HH_; i += 512){
      const int r = i >> 7, k = i & 127;
      ((float*)lw4)[((k >> 2)*VW + r)*4 + (k & 3)] = fcw[(size_t)(v0 + r)*HH_ + k];
    }
    float fb[5];
#pragma unroll
    for (int vi = 0; vi < 5; ++vi) fb[vi] = fcb[v0 + vi*32 + vg];
    __syncthreads();
#pragma unroll 1
    for (int s = 0; s < TT_; ++s){
      // poll h DATA directly: 4 u64 per thread, distinct lines, no shared flag.
      {
        const unsigned long long* hs = hq + (size_t)s*BB_*64 + t*4;
        unsigned long long g0 = 0, g1 = 0, g2 = 0, g3 = 0;
        for (;;){
          if (!g0) g0 = aload64(hs + 0);
          if (!g1) g1 = aload64(hs + 1);
          if (!g2) g2 = aload64(hs + 2);
          if (!g3) g3 = aload64(hs + 3);
          if (g0 && g1 && g2 && g3) break;
          __builtin_amdgcn_s_sleep(1);
        }
        // unpack (subtract sentinel bias) straight into LDS: u64 i -> b=i>>6, pair=i&63
        const int i0 = t*4;
        const int bb = i0 >> 6, p0 = i0 & 63;
        float2 f0, f1, f2, f3;
        f0.x = __uint_as_float((unsigned)g0) - 2.0f; f0.y = __uint_as_float((unsigned)(g0>>32)) - 2.0f;
        f1.x = __uint_as_float((unsigned)g1) - 2.0f; f1.y = __uint_as_float((unsigned)(g1>>32)) - 2.0f;
        f2.x = __uint_as_float((unsigned)g2) - 2.0f; f2.y = __uint_as_float((unsigned)(g2>>32)) - 2.0f;
        f3.x = __uint_as_float((unsigned)g3) - 2.0f; f3.y = __uint_as_float((unsigned)(g3>>32)) - 2.0f;
        float* dst = &lhb[bb*HH_ + 2*p0];
        *(float2*)(dst+0) = f0; *(float2*)(dst+2) = f1;
        *(float2*)(dst+4) = f2; *(float2*)(dst+6) = f3;
      }
      __syncthreads();
      float acc[5][8];
#pragma unroll
      for (int vi = 0; vi < 5; ++vi)
#pragma unroll
        for (int bi = 0; bi < 8; ++bi) acc[vi][bi] = 0.f;
      const int kb = ks * 8;      // 8 float4-chunks (32 k) per ks
#pragma unroll
      for (int kc = 0; kc < 8; ++kc){
        const int kcc = kb + kc;
        float4 w[5];
#pragma unroll
        for (int vi = 0; vi < 5; ++vi) w[vi] = lw4[kcc*VW + vi*32 + vg];  // read ONCE per kc
#pragma unroll
        for (int bi = 0; bi < 8; ++bi){
          const float4 hb = *(const float4*)&lhb[(bg*8 + bi)*HH_ + kcc*4];  // broadcast read
#pragma unroll
          for (int vi = 0; vi < 5; ++vi)
            acc[vi][bi] = fmaf(w[vi].x,hb.x,fmaf(w[vi].y,hb.y,fmaf(w[vi].z,hb.z,fmaf(w[vi].w,hb.w,acc[vi][bi]))));
        }
      }
      // k-split reduce: ks=1..3 publish, ks=0 combines (stride-41 dwords)
      if (ks){
        float* dst = rdf + ((size_t)(ks-1)*128 + u)*41;
#pragma unroll
        for (int vi = 0; vi < 5; ++vi)
#pragma unroll
          for (int bi = 0; bi < 8; ++bi) dst[vi*8 + bi] = acc[vi][bi];
      }
      __syncthreads();
      if (ks == 0){
#pragma unroll
        for (int r = 0; r < 3; ++r){
          const float* src = rdf + ((size_t)r*128 + u)*41;
#pragma unroll
          for (int vi = 0; vi < 5; ++vi)
#pragma unroll
            for (int bi = 0; bi < 8; ++bi) acc[vi][bi] += src[vi*8 + bi];
        }
#pragma unroll
        for (int vi = 0; vi < 5; ++vi)
#pragma unroll
          for (int bi = 0; bi < 8; ++bi) acc[vi][bi] += fb[vi];
        // per-batch argmax over this wg's 160 rows -> ONE sentinel store per (wg,batch)
#pragma unroll
        for (int bi = 0; bi < 8; ++bi){
          unsigned long long best = 0ull;
#pragma unroll
          for (int vi = 0; vi < 5; ++vi){
            const unsigned long long pk = packmax(acc[vi][bi], v0 + vi*32 + vg);
            if (pk > best) best = pk;
          }
#pragma unroll
          for (int off = 16; off > 0; off >>= 1){
            const unsigned long long o = __shfl_xor(best, off);
            if (o > best) best = o;
          }
          if (vg == 0)
            astore64(&part[((size_t)s*NMM + widx)*BB_ + bg*8 + bi], best);
        }
        // logits after publication (nontemporal; drains during next poll window)
#pragma unroll
        for (int bi = 0; bi < 8; ++bi){
          float* orow = out + ((size_t)(bg*8 + bi)*TT_ + s)*(size_t)VV_ + v0;
#pragma unroll
          for (int vi = 0; vi < 5; ++vi)
            __builtin_nontemporal_store(acc[vi][bi], &orow[vi*32 + vg]);
        }
      }
    }
  }
}

extern "C" void kernel_launch(void* const* d_in, const int* in_sizes, int n_in,
                              void* d_out, int out_size, void* d_ws, size_t ws_size,
                              hipStream_t stream){
  (void)in_sizes; (void)n_in; (void)out_size; (void)ws_size;
  const int*   x     = (const int*)  d_in[0];
  const float* embed = (const float*)d_in[1];
  const float* eWih  = (const float*)d_in[2];
  const float* eWhh  = (const float*)d_in[3];
  const float* eb    = (const float*)d_in[4];
  const float* dWih  = (const float*)d_in[5];
  const float* dWhh  = (const float*)d_in[6];
  const float* db    = (const float*)d_in[7];
  const float* fcw   = (const float*)d_in[8];
  const float* fcb   = (const float*)d_in[9];
  float* out = (float*)d_out;
  char* ws = (char*)d_ws;
  unsigned long long* hq   = (unsigned long long*)(ws + WS_HQ);
  unsigned long long* part = (unsigned long long*)(ws + WS_PART);
  float* h_enc = (float*)(ws + WS_HENC);
  float* c_enc = (float*)(ws + WS_CENC);

  // zero the sentinel buffers every launch (graph node -> deterministic replays,
  // and clears the harness's 0xAA poison which would defeat the sentinels)
  (void)hipMemsetAsync(ws, 0, WS_ZEND, stream);
  // allow >64KB dynamic LDS (gfx950 has 160KB/CU); idempotent host-side call
  (void)hipFuncSetAttribute((const void*)dec_kernel, hipFuncAttributeMaxDynamicSharedMemorySize, DYN_LDS);

  enc_kernel<<<NCELL, 512, 0, stream>>>(x, embed, eWih, eWhh, eb, h_enc, c_enc);
  dec_kernel<<<NWG, 512, DYN_LDS, stream>>>(embed, dWih, dWhh, db, fcw, fcb,
                                            h_enc, c_enc, hq, part, out);
}

// Round 10
// 2270.017 us; speedup vs baseline: 6.8128x; 1.5039x over previous
//
#include <hip/hip_runtime.h>
#include <math.h>

#define BB_ 32
#define TT_ 128
#define EE_ 64
#define HH_ 128
#define VV_ 32000
#define NMM 200      // matmul workgroups
#define NCELL 32     // cell workgroups (one per batch)
#define NWG (NMM + NCELL)
#define VW 160       // vocab rows per matmul wg (200*160 = 32000)

// ---- dynamic LDS layout (bytes) for matmul wgs ----
#define OFF_LW  0                   // float4[32 kcc][160 r] = 81920  fc_w slice
#define OFF_LHB 81920               // float[32 b][128 k]    = 16384  h tile
#define OFF_RDF 98304               // float[3*128]*41dw     = 62976  k-split reduce
// cell wgs overlay (same dynamic buffer, different CUs)
#define OFF_SG  0                   // float[512] gates
#define OFF_SH  2048                // float[128] h
#define OFF_TOK 2560                // int token broadcast
#define OFF_R64 2568                // u64[8] wave argmax partials
#define DYN_LDS 161280              // 157.5KB -> 1 wg/CU (160KB pool)

// ---- workspace layout (bytes) ----
// h-link: agent-atomic u32 h stores -> LLC; per-batch plain sentinel (1 line/step);
//         readers use PLAIN CACHED loads (per-XCD L2 multicast; R8-verified).
// part-link: data IS the sentinel (packmax nonzero); reader-contiguous [s][b][widx].
#define WS_HQ    0                                          // f32[TT][BB][HH] = 2,097,152
#define WS_PART  (TT_*BB_*HH_*4)                            // u64[TT][BB][NMM] = 6,553,600
#define WS_HSENT (WS_PART + TT_*BB_*NMM*8)                  // u32[TT][BB] = 16,384
#define WS_ZEND  (WS_HSENT + TT_*BB_*4)                     // zero [0, WS_ZEND) each launch
#define WS_HENC  WS_ZEND                                    // f32[BB*HH]
#define WS_CENC  (WS_HENC + BB_*HH_*4)                      // f32[BB*HH]
#define WS_END   (WS_CENC + BB_*HH_*4)

__device__ __forceinline__ float rlane(float v, int l){
  return __int_as_float(__builtin_amdgcn_readlane(__float_as_int(v), l));
}
__device__ __forceinline__ float sigm(float x){ return 1.f / (1.f + expf(-x)); }

__device__ __forceinline__ unsigned long long packmax(float v, int idx){
  unsigned u = __float_as_uint(v);
  u = (u & 0x80000000u) ? ~u : (u | 0x80000000u);   // monotone float->uint map
  return ((unsigned long long)u << 32) | (unsigned long long)(0xFFFFFFFFu - (unsigned)idx);
}

__device__ __forceinline__ unsigned aload32(const unsigned* p){
  return __hip_atomic_load(p, __ATOMIC_RELAXED, __HIP_MEMORY_SCOPE_AGENT);
}
__device__ __forceinline__ unsigned long long aload64(const unsigned long long* p){
  return __hip_atomic_load(p, __ATOMIC_RELAXED, __HIP_MEMORY_SCOPE_AGENT);
}
__device__ __forceinline__ void astore32(unsigned* p, unsigned v){
  __hip_atomic_store(p, v, __ATOMIC_RELAXED, __HIP_MEMORY_SCOPE_AGENT);
}
__device__ __forceinline__ void astore64(unsigned long long* p, unsigned long long v){
  __hip_atomic_store(p, v, __ATOMIC_RELAXED, __HIP_MEMORY_SCOPE_AGENT);
}

// Whh[row t]·h : 32 float4 L2-stream + readlane broadcasts. Runs in the mm window.
__device__ __forceinline__ float whh_dot(const float* wrow, float h0, float h1){
  const float4* hp = (const float4*)wrow;
  asm volatile("" : "+v"(hp));        // opaque: keep loads inside the loop iteration
  float b0 = 0.f, b1 = 0.f, b2 = 0.f, b3 = 0.f;
#pragma unroll
  for (int q = 0; q < 16; ++q){
    const float4 w = hp[q];
    b0 = fmaf(w.x, rlane(h0, q*4+0), b0);
    b1 = fmaf(w.y, rlane(h0, q*4+1), b1);
    b2 = fmaf(w.z, rlane(h0, q*4+2), b2);
    b3 = fmaf(w.w, rlane(h0, q*4+3), b3);
  }
#pragma unroll
  for (int q = 0; q < 16; ++q){
    const float4 w = hp[16+q];
    b0 = fmaf(w.x, rlane(h1, q*4+0), b0);
    b1 = fmaf(w.y, rlane(h1, q*4+1), b1);
    b2 = fmaf(w.z, rlane(h1, q*4+2), b2);
    b3 = fmaf(w.w, rlane(h1, q*4+3), b3);
  }
  return (b0 + b1) + (b2 + b3);
}

// register-resident full gate dot (encoder)
__device__ __forceinline__ float gate_dot_r(const float (&wih)[EE_], const float (&whh)[HH_],
                                            float bias, float xe, float h0, float h1){
  float a0 = bias, a1 = 0.f, a2 = 0.f, a3 = 0.f;
#pragma unroll
  for (int e = 0; e < EE_; e += 4){
    a0 = fmaf(wih[e+0], rlane(xe, e+0), a0);
    a1 = fmaf(wih[e+1], rlane(xe, e+1), a1);
    a2 = fmaf(wih[e+2], rlane(xe, e+2), a2);
    a3 = fmaf(wih[e+3], rlane(xe, e+3), a3);
  }
#pragma unroll
  for (int j = 0; j < 64; j += 4){
    a0 = fmaf(whh[j+0], rlane(h0, j+0), a0);
    a1 = fmaf(whh[j+1], rlane(h0, j+1), a1);
    a2 = fmaf(whh[j+2], rlane(h0, j+2), a2);
    a3 = fmaf(whh[j+3], rlane(h0, j+3), a3);
  }
#pragma unroll
  for (int j = 0; j < 64; j += 4){
    a0 = fmaf(whh[64+j+0], rlane(h1, j+0), a0);
    a1 = fmaf(whh[64+j+1], rlane(h1, j+1), a1);
    a2 = fmaf(whh[64+j+2], rlane(h1, j+2), a2);
    a3 = fmaf(whh[64+j+3], rlane(h1, j+3), a3);
  }
  return (a0 + a1) + (a2 + a3);
}

// ===================== encoder: 32 wgs (one per batch), no cross-wg deps =====================
__global__ __launch_bounds__(512)
void enc_kernel(const int* __restrict__ xt, const float* __restrict__ embed,
                const float* __restrict__ Wih, const float* __restrict__ Whh,
                const float* __restrict__ bv,
                float* __restrict__ h_out, float* __restrict__ c_out)
{
  const int b = blockIdx.x, t = threadIdx.x, lane = t & 63;
  __shared__ float sh[HH_];
  __shared__ float sg[4*HH_];
  float wih[EE_], whh[HH_];
#pragma unroll
  for (int e = 0; e < EE_; ++e) wih[e] = Wih[t*EE_ + e];
#pragma unroll
  for (int j = 0; j < HH_; ++j) whh[j] = Whh[t*HH_ + j];
  const float bias = bv[t];
  float c = 0.f, hv = 0.f;
  if (t < HH_) sh[t] = 0.f;
  __syncthreads();
#pragma unroll 1
  for (int s = 0; s < TT_; ++s){
    const int tok = xt[b*TT_ + s];
    const float xe = embed[tok*EE_ + lane];
    const float h0 = sh[lane], h1 = sh[64 + lane];
    const float g = gate_dot_r(wih, whh, bias, xe, h0, h1);
    __syncthreads();   // all sh reads done
    sg[t] = g;
    __syncthreads();
    if (t < HH_){
      const float gi = sg[t], gf = sg[128+t], gg = sg[256+t], go = sg[384+t];
      c = sigm(gf)*c + sigm(gi)*tanhf(gg);
      hv = sigm(go)*tanhf(c);
      sh[t] = hv;
    }
    __syncthreads();
  }
  if (t < HH_){ h_out[b*HH_ + t] = hv; c_out[b*HH_ + t] = c; }
}

// ===================== decoder: persistent, 32 cell wgs + 200 matmul wgs =====================
__global__ __launch_bounds__(512)
void dec_kernel(const float* __restrict__ embed,
                const float* __restrict__ dWih, const float* __restrict__ dWhh,
                const float* __restrict__ db,
                const float* __restrict__ fcw, const float* __restrict__ fcb,
                const float* __restrict__ h_enc, const float* __restrict__ c_enc,
                float* __restrict__ hq, unsigned long long* __restrict__ part,
                unsigned* __restrict__ hsent, float* __restrict__ out)
{
  extern __shared__ char smem[];
  const int t = threadIdx.x;
  const int wg = blockIdx.x;

  if (wg < NCELL){
    // ---------------- cell workgroup: owns batch b (pipelined gate) ----------------
    float* sg = (float*)(smem + OFF_SG);
    float* sh = (float*)(smem + OFF_SH);
    int* stok = (int*)(smem + OFF_TOK);
    unsigned long long* r64 = (unsigned long long*)(smem + OFF_R64);
    const int b = wg, lane = t & 63;
    const float bias = db[t];
    float wih[EE_];                       // x-part weights live in REGISTERS
#pragma unroll
    for (int e = 0; e < EE_; ++e) wih[e] = dWih[t*EE_ + e];
    float c = 0.f;
    if (t < HH_){ c = c_enc[b*HH_ + t]; sh[t] = h_enc[b*HH_ + t]; }
    int tok = 1; // SOS
    __syncthreads();
    // Whh·h for the first step (h_enc), off the critical chain
    float hacc = whh_dot(dWhh + t*HH_, sh[lane], sh[64 + lane]);
#pragma unroll 1
    for (int s = 0; s < TT_; ++s){
      // token-dependent part only: 64 reg-FMAs + one embed row
      const float xe = embed[tok*EE_ + lane];
      float a0 = bias + hacc, a1 = 0.f, a2 = 0.f, a3 = 0.f;
#pragma unroll
      for (int e = 0; e < EE_; e += 4){
        a0 = fmaf(wih[e+0], rlane(xe, e+0), a0);
        a1 = fmaf(wih[e+1], rlane(xe, e+1), a1);
        a2 = fmaf(wih[e+2], rlane(xe, e+2), a2);
        a3 = fmaf(wih[e+3], rlane(xe, e+3), a3);
      }
      sg[t] = (a0 + a1) + (a2 + a3);
      __syncthreads();
      if (t < HH_){
        const float gi = sg[t], gf = sg[128+t], gg = sg[256+t], go = sg[384+t];
        c = sigm(gf)*c + sigm(gi)*tanhf(gg);
        const float hv = sigm(go)*tanhf(c);
        sh[t] = hv;
        __hip_atomic_store((unsigned*)&hq[(size_t)s*BB_*HH_ + b*HH_ + t],
                           __float_as_uint(hv), __ATOMIC_RELAXED, __HIP_MEMORY_SCOPE_AGENT);
      }
      __syncthreads();          // sh ready AND all waves' h stores drained (vmcnt0 at barrier)
      if (t == 0) astore32(&hsent[s*BB_ + b], 1u);
      // overlapped with the mm window: Whh·h for the NEXT step
      const float hacc_n = whh_dot(dWhh + t*HH_, sh[lane], sh[64 + lane]);
      // poll this batch's 200 argmax partials (data IS the sentinel; contiguous 25 lines)
      unsigned long long m = 0ull;
      if (t < NMM){
        const unsigned long long* pp = part + ((size_t)s*BB_ + b)*NMM + t;
        while (!(m = aload64(pp))) __builtin_amdgcn_s_sleep(1);
      }
#pragma unroll
      for (int off = 32; off > 0; off >>= 1){
        const unsigned long long o = __shfl_xor(m, off);
        if (o > m) m = o;
      }
      if ((t & 63) == 0) r64[t >> 6] = m;
      __syncthreads();
      if (t == 0){
        unsigned long long best = r64[0];
#pragma unroll
        for (int w = 1; w < 8; ++w) if (r64[w] > best) best = r64[w];
        *stok = (int)(0xFFFFFFFFu - (unsigned)(best & 0xFFFFFFFFull));
      }
      __syncthreads();
      tok = *stok;
      hacc = hacc_n;
    }
  } else {
    // ---------------- matmul workgroup: vocab rows [v0, v0+VW) ----------------
    const int widx = wg - NCELL;
    const int v0 = widx * VW;
    float4* lw4 = (float4*)(smem + OFF_LW);   // [kcc][r]
    float*  lhb = (float*)(smem + OFF_LHB);   // [b][k], stride 128
    float*  rdf = (float*)(smem + OFF_RDF);
    const int ks = t >> 7;          // k-split quarter: k in [ks*32, ks*32+32)
    const int u  = t & 127;
    const int vg = u & 31;          // vocab lane; row v = v0 + vi*32 + vg
    const int bg = u >> 5;          // batch group (8 batches each)
    // stage fc_w slice into LDS once (reused for all 128 steps)
    for (int i = t; i < VW*HH_; i += 512){
      const int r = i >> 7, k = i & 127;
      ((float*)lw4)[((k >> 2)*VW + r)*4 + (k & 3)] = fcw[(size_t)(v0 + r)*HH_ + k];
    }
    float fb[5];
#pragma unroll
    for (int vi = 0; vi < 5; ++vi) fb[vi] = fcb[v0 + vi*32 + vg];
    __syncthreads();
#pragma unroll 1
    for (int s = 0; s < TT_; ++s){
      // poll ONE line of per-batch sentinels (wave 0 only)
      if (t < 64){
        unsigned v = (t < 32) ? 0u : 1u;
        for (;;){
          if (!v) v = aload32(&hsent[s*BB_ + t]);
          if (__all(v != 0)) break;
          __builtin_amdgcn_s_sleep(1);
        }
      }
      __syncthreads();
      // PLAIN cached, coalesced h stage (16KB; per-XCD L2 multicasts across 25 wgs)
      const float4* hsrc = (const float4*)(hq + (size_t)s*BB_*HH_);
#pragma unroll
      for (int i = t; i < BB_*HH_/4; i += 512){
        const float4 v = hsrc[i];
        const int bb = i >> 5, k4 = i & 31;
        *(float4*)&lhb[bb*HH_ + k4*4] = v;
      }
      __syncthreads();
      float acc[5][8];
#pragma unroll
      for (int vi = 0; vi < 5; ++vi)
#pragma unroll
        for (int bi = 0; bi < 8; ++bi) acc[vi][bi] = 0.f;
      const int kb = ks * 8;      // 8 float4-chunks (32 k) per ks
#pragma unroll
      for (int kc = 0; kc < 8; ++kc){
        const int kcc = kb + kc;
        float4 w[5];
#pragma unroll
        for (int vi = 0; vi < 5; ++vi) w[vi] = lw4[kcc*VW + vi*32 + vg];  // read ONCE per kc
#pragma unroll
        for (int bi = 0; bi < 8; ++bi){
          const float4 hb = *(const float4*)&lhb[(bg*8 + bi)*HH_ + kcc*4];  // broadcast read
#pragma unroll
          for (int vi = 0; vi < 5; ++vi)
            acc[vi][bi] = fmaf(w[vi].x,hb.x,fmaf(w[vi].y,hb.y,fmaf(w[vi].z,hb.z,fmaf(w[vi].w,hb.w,acc[vi][bi]))));
        }
      }
      // k-split reduce: ks=1..3 publish, ks=0 combines (stride-41 dwords)
      if (ks){
        float* dst = rdf + ((size_t)(ks-1)*128 + u)*41;
#pragma unroll
        for (int vi = 0; vi < 5; ++vi)
#pragma unroll
          for (int bi = 0; bi < 8; ++bi) dst[vi*8 + bi] = acc[vi][bi];
      }
      __syncthreads();
      if (ks == 0){
#pragma unroll
        for (int r = 0; r < 3; ++r){
          const float* src = rdf + ((size_t)r*128 + u)*41;
#pragma unroll
          for (int vi = 0; vi < 5; ++vi)
#pragma unroll
            for (int bi = 0; bi < 8; ++bi) acc[vi][bi] += src[vi*8 + bi];
        }
#pragma unroll
        for (int vi = 0; vi < 5; ++vi)
#pragma unroll
          for (int bi = 0; bi < 8; ++bi) acc[vi][bi] += fb[vi];
        // per-batch argmax over this wg's 160 rows -> ONE sentinel store per (wg,batch)
#pragma unroll
        for (int bi = 0; bi < 8; ++bi){
          unsigned long long best = 0ull;
#pragma unroll
          for (int vi = 0; vi < 5; ++vi){
            const unsigned long long pk = packmax(acc[vi][bi], v0 + vi*32 + vg);
            if (pk > best) best = pk;
          }
#pragma unroll
          for (int off = 16; off > 0; off >>= 1){
            const unsigned long long o = __shfl_xor(best, off);
            if (o > best) best = o;
          }
          if (vg == 0)
            astore64(&part[((size_t)s*BB_ + bg*8 + bi)*NMM + widx], best);
        }
        // logits after publication (nontemporal; drain during next poll window)
#pragma unroll
        for (int bi = 0; bi < 8; ++bi){
          float* orow = out + ((size_t)(bg*8 + bi)*TT_ + s)*(size_t)VV_ + v0;
#pragma unroll
          for (int vi = 0; vi < 5; ++vi)
            __builtin_nontemporal_store(acc[vi][bi], &orow[vi*32 + vg]);
        }
      }
    }
  }
}

extern "C" void kernel_launch(void* const* d_in, const int* in_sizes, int n_in,
                              void* d_out, int out_size, void* d_ws, size_t ws_size,
                              hipStream_t stream){
  (void)in_sizes; (void)n_in; (void)out_size; (void)ws_size;
  const int*   x     = (const int*)  d_in[0];
  const float* embed = (const float*)d_in[1];
  const float* eWih  = (const float*)d_in[2];
  const float* eWhh  = (const float*)d_in[3];
  const float* eb    = (const float*)d_in[4];
  const float* dWih  = (const float*)d_in[5];
  const float* dWhh  = (const float*)d_in[6];
  const float* db    = (const float*)d_in[7];
  const float* fcw   = (const float*)d_in[8];
  const float* fcb   = (const float*)d_in[9];
  float* out = (float*)d_out;
  char* ws = (char*)d_ws;
  float* hq = (float*)(ws + WS_HQ);
  unsigned long long* part = (unsigned long long*)(ws + WS_PART);
  unsigned* hsent = (unsigned*)(ws + WS_HSENT);
  float* h_enc = (float*)(ws + WS_HENC);
  float* c_enc = (float*)(ws + WS_CENC);

  // zero sentinel/data buffers every launch (graph node -> deterministic replays,
  // clears the harness 0xAA poison which would defeat the sentinels)
  (void)hipMemsetAsync(ws, 0, WS_ZEND, stream);
  // allow >64KB dynamic LDS (gfx950 has 160KB/CU); idempotent host-side call
  (void)hipFuncSetAttribute((const void*)dec_kernel, hipFuncAttributeMaxDynamicSharedMemorySize, DYN_LDS);

  enc_kernel<<<NCELL, 512, 0, stream>>>(x, embed, eWih, eWhh, eb, h_enc, c_enc);
  dec_kernel<<<NWG, 512, DYN_LDS, stream>>>(embed, dWih, dWhh, db, fcw, fcb,
                                            h_enc, c_enc, hq, part, hsent, out);
}

// Round 11
// 2258.113 us; speedup vs baseline: 6.8487x; 1.0053x over previous
//
#include <hip/hip_runtime.h>
#include <math.h>

#define BB_ 32
#define TT_ 128
#define EE_ 64
#define HH_ 128
#define VV_ 32000
#define NMM 200      // matmul workgroups
#define NCELL 32     // cell workgroups (one per batch)
#define NWG (NMM + NCELL)
#define VW 160       // vocab rows per matmul wg (200*160 = 32000)

// ---- dynamic LDS layout (bytes) for matmul wgs ----
#define OFF_LW  0                   // float4[32 kcc][160 r] = 81920  fc_w slice
#define OFF_LHB 81920               // float[32 b][128 k]    = 16384  h tile
#define OFF_RDF 98304               // float[3*128]*41dw     = 62976  k-split reduce
// cell wgs overlay (same dynamic buffer, different CUs)
#define OFF_SG  0                   // float[512] gates
#define OFF_SH  2048                // float[128] h
#define OFF_TOK 2560                // int token broadcast
#define OFF_R64 2568                // u64[8] wave argmax partials
#define DYN_LDS 161280              // 157.5KB -> 1 wg/CU (160KB pool)

// ---- workspace layout (bytes) ----
// h-link: agent-atomic u32 h stores -> LLC; per-batch plain sentinel (1 line/step);
//         readers use PLAIN CACHED loads (per-XCD L2 multicast; R8/R10-verified).
// part-link: data IS the sentinel (packmax nonzero); reader-contiguous [s][b][widx].
#define WS_HQ    0                                          // f32[TT][BB][HH] = 2,097,152
#define WS_PART  (TT_*BB_*HH_*4)                            // u64[TT][BB][NMM] = 6,553,600
#define WS_HSENT (WS_PART + TT_*BB_*NMM*8)                  // u32[TT][BB] = 16,384
#define WS_ZEND  (WS_HSENT + TT_*BB_*4)                     // zero [0, WS_ZEND) each launch
#define WS_HENC  WS_ZEND                                    // f32[BB*HH]
#define WS_CENC  (WS_HENC + BB_*HH_*4)                      // f32[BB*HH]
#define WS_END   (WS_CENC + BB_*HH_*4)

__device__ __forceinline__ float rlane(float v, int l){
  return __int_as_float(__builtin_amdgcn_readlane(__float_as_int(v), l));
}
__device__ __forceinline__ float sigm(float x){ return 1.f / (1.f + expf(-x)); }

__device__ __forceinline__ unsigned long long packmax(float v, int idx){
  unsigned u = __float_as_uint(v);
  u = (u & 0x80000000u) ? ~u : (u | 0x80000000u);   // monotone float->uint map
  return ((unsigned long long)u << 32) | (unsigned long long)(0xFFFFFFFFu - (unsigned)idx);
}

__device__ __forceinline__ unsigned aload32(const unsigned* p){
  return __hip_atomic_load(p, __ATOMIC_RELAXED, __HIP_MEMORY_SCOPE_AGENT);
}
__device__ __forceinline__ unsigned long long aload64(const unsigned long long* p){
  return __hip_atomic_load(p, __ATOMIC_RELAXED, __HIP_MEMORY_SCOPE_AGENT);
}
__device__ __forceinline__ void astore32(unsigned* p, unsigned v){
  __hip_atomic_store(p, v, __ATOMIC_RELAXED, __HIP_MEMORY_SCOPE_AGENT);
}
__device__ __forceinline__ void astore64(unsigned long long* p, unsigned long long v){
  __hip_atomic_store(p, v, __ATOMIC_RELAXED, __HIP_MEMORY_SCOPE_AGENT);
}

// Whh[row t]·h : 32 float4 L2-stream + readlane broadcasts. Runs in the mm window.
__device__ __forceinline__ float whh_dot(const float* wrow, float h0, float h1){
  const float4* hp = (const float4*)wrow;
  asm volatile("" : "+v"(hp));        // opaque: keep loads inside the loop iteration
  float b0 = 0.f, b1 = 0.f, b2 = 0.f, b3 = 0.f;
#pragma unroll
  for (int q = 0; q < 16; ++q){
    const float4 w = hp[q];
    b0 = fmaf(w.x, rlane(h0, q*4+0), b0);
    b1 = fmaf(w.y, rlane(h0, q*4+1), b1);
    b2 = fmaf(w.z, rlane(h0, q*4+2), b2);
    b3 = fmaf(w.w, rlane(h0, q*4+3), b3);
  }
#pragma unroll
  for (int q = 0; q < 16; ++q){
    const float4 w = hp[16+q];
    b0 = fmaf(w.x, rlane(h1, q*4+0), b0);
    b1 = fmaf(w.y, rlane(h1, q*4+1), b1);
    b2 = fmaf(w.z, rlane(h1, q*4+2), b2);
    b3 = fmaf(w.w, rlane(h1, q*4+3), b3);
  }
  return (b0 + b1) + (b2 + b3);
}

// register-resident full gate dot (encoder)
__device__ __forceinline__ float gate_dot_r(const float (&wih)[EE_], const float (&whh)[HH_],
                                            float bias, float xe, float h0, float h1){
  float a0 = bias, a1 = 0.f, a2 = 0.f, a3 = 0.f;
#pragma unroll
  for (int e = 0; e < EE_; e += 4){
    a0 = fmaf(wih[e+0], rlane(xe, e+0), a0);
    a1 = fmaf(wih[e+1], rlane(xe, e+1), a1);
    a2 = fmaf(wih[e+2], rlane(xe, e+2), a2);
    a3 = fmaf(wih[e+3], rlane(xe, e+3), a3);
  }
#pragma unroll
  for (int j = 0; j < 64; j += 4){
    a0 = fmaf(whh[j+0], rlane(h0, j+0), a0);
    a1 = fmaf(whh[j+1], rlane(h0, j+1), a1);
    a2 = fmaf(whh[j+2], rlane(h0, j+2), a2);
    a3 = fmaf(whh[j+3], rlane(h0, j+3), a3);
  }
#pragma unroll
  for (int j = 0; j < 64; j += 4){
    a0 = fmaf(whh[64+j+0], rlane(h1, j+0), a0);
    a1 = fmaf(whh[64+j+1], rlane(h1, j+1), a1);
    a2 = fmaf(whh[64+j+2], rlane(h1, j+2), a2);
    a3 = fmaf(whh[64+j+3], rlane(h1, j+3), a3);
  }
  return (a0 + a1) + (a2 + a3);
}

// ===================== encoder: 32 wgs (one per batch), no cross-wg deps =====================
__global__ __launch_bounds__(512)
void enc_kernel(const int* __restrict__ xt, const float* __restrict__ embed,
                const float* __restrict__ Wih, const float* __restrict__ Whh,
                const float* __restrict__ bv,
                float* __restrict__ h_out, float* __restrict__ c_out)
{
  const int b = blockIdx.x, t = threadIdx.x, lane = t & 63;
  __shared__ float sh[HH_];
  __shared__ float sg[4*HH_];
  float wih[EE_], whh[HH_];
#pragma unroll
  for (int e = 0; e < EE_; ++e) wih[e] = Wih[t*EE_ + e];
#pragma unroll
  for (int j = 0; j < HH_; ++j) whh[j] = Whh[t*HH_ + j];
  const float bias = bv[t];
  float c = 0.f, hv = 0.f;
  if (t < HH_) sh[t] = 0.f;
  __syncthreads();
#pragma unroll 1
  for (int s = 0; s < TT_; ++s){
    const int tok = xt[b*TT_ + s];
    const float xe = embed[tok*EE_ + lane];
    const float h0 = sh[lane], h1 = sh[64 + lane];
    const float g = gate_dot_r(wih, whh, bias, xe, h0, h1);
    __syncthreads();   // all sh reads done
    sg[t] = g;
    __syncthreads();
    if (t < HH_){
      const float gi = sg[t], gf = sg[128+t], gg = sg[256+t], go = sg[384+t];
      c = sigm(gf)*c + sigm(gi)*tanhf(gg);
      hv = sigm(go)*tanhf(c);
      sh[t] = hv;
    }
    __syncthreads();
  }
  if (t < HH_){ h_out[b*HH_ + t] = hv; c_out[b*HH_ + t] = c; }
}

// ===================== decoder: persistent, 32 cell wgs + 200 matmul wgs =====================
__global__ __launch_bounds__(512)
void dec_kernel(const float* __restrict__ embed,
                const float* __restrict__ dWih, const float* __restrict__ dWhh,
                const float* __restrict__ db,
                const float* __restrict__ fcw, const float* __restrict__ fcb,
                const float* __restrict__ h_enc, const float* __restrict__ c_enc,
                float* __restrict__ hq, unsigned long long* __restrict__ part,
                unsigned* __restrict__ hsent, float* __restrict__ out)
{
  extern __shared__ char smem[];
  const int t = threadIdx.x;
  const int wg = blockIdx.x;

  if (wg < NCELL){
    // ---------------- cell workgroup: owns batch b (pipelined gate) ----------------
    float* sg = (float*)(smem + OFF_SG);
    float* sh = (float*)(smem + OFF_SH);
    int* stok = (int*)(smem + OFF_TOK);
    unsigned long long* r64 = (unsigned long long*)(smem + OFF_R64);
    const int b = wg, lane = t & 63;
    const float bias = db[t];
    float wih[EE_];                       // x-part weights live in REGISTERS
#pragma unroll
    for (int e = 0; e < EE_; ++e) wih[e] = dWih[t*EE_ + e];
    float c = 0.f;
    if (t < HH_){ c = c_enc[b*HH_ + t]; sh[t] = h_enc[b*HH_ + t]; }
    int tok = 1; // SOS
    __syncthreads();
    // Whh·h for the first step (h_enc), off the critical chain
    float hacc = whh_dot(dWhh + t*HH_, sh[lane], sh[64 + lane]);
#pragma unroll 1
    for (int s = 0; s < TT_; ++s){
      // token-dependent part only: 64 reg-FMAs + one (prefetched) embed row
      const float xe = embed[tok*EE_ + lane];
      float a0 = bias + hacc, a1 = 0.f, a2 = 0.f, a3 = 0.f;
#pragma unroll
      for (int e = 0; e < EE_; e += 4){
        a0 = fmaf(wih[e+0], rlane(xe, e+0), a0);
        a1 = fmaf(wih[e+1], rlane(xe, e+1), a1);
        a2 = fmaf(wih[e+2], rlane(xe, e+2), a2);
        a3 = fmaf(wih[e+3], rlane(xe, e+3), a3);
      }
      sg[t] = (a0 + a1) + (a2 + a3);
      __syncthreads();
      if (t < HH_){
        const float gi = sg[t], gf = sg[128+t], gg = sg[256+t], go = sg[384+t];
        c = sigm(gf)*c + sigm(gi)*tanhf(gg);
        const float hv = sigm(go)*tanhf(c);
        sh[t] = hv;
        __hip_atomic_store((unsigned*)&hq[(size_t)s*BB_*HH_ + b*HH_ + t],
                           __float_as_uint(hv), __ATOMIC_RELAXED, __HIP_MEMORY_SCOPE_AGENT);
      }
      __syncthreads();          // sh ready AND all waves' h stores drained (vmcnt0 at barrier)
      if (t == 0) astore32(&hsent[s*BB_ + b], 1u);
      // overlapped with the mm window: Whh·h for the NEXT step
      const float hacc_n = whh_dot(dWhh + t*HH_, sh[lane], sh[64 + lane]);
      // busy-spin poll of this batch's 200 argmax partials (data IS the sentinel);
      // as each candidate arrives, touch its embed row -> winner is cache-hot.
      unsigned long long m = 0ull;
      if (t < NMM){
        const unsigned long long* pp = part + ((size_t)s*BB_ + b)*NMM + t;
        bool pf = false;
        for (;;){
          if (!m) m = aload64(pp);
          if (m && !pf){
            pf = true;
            const unsigned idx = 0xFFFFFFFFu - (unsigned)(m & 0xFFFFFFFFull);
            const float* er = embed + (size_t)idx*EE_;
            const float p0 = er[0], p1 = er[32];     // both 128B lines of the row
            asm volatile("" :: "v"(p0), "v"(p1));    // keep the touch loads alive
          }
          if (__all(m != 0)) break;
        }
      }
#pragma unroll
      for (int off = 32; off > 0; off >>= 1){
        const unsigned long long o = __shfl_xor(m, off);
        if (o > m) m = o;
      }
      if ((t & 63) == 0) r64[t >> 6] = m;
      __syncthreads();
      if (t == 0){
        unsigned long long best = r64[0];
#pragma unroll
        for (int w = 1; w < 8; ++w) if (r64[w] > best) best = r64[w];
        *stok = (int)(0xFFFFFFFFu - (unsigned)(best & 0xFFFFFFFFull));
      }
      __syncthreads();
      tok = *stok;
      hacc = hacc_n;
    }
  } else {
    // ---------------- matmul workgroup: vocab rows [v0, v0+VW) ----------------
    const int widx = wg - NCELL;
    const int v0 = widx * VW;
    float4* lw4 = (float4*)(smem + OFF_LW);   // [kcc][r]
    float*  lhb = (float*)(smem + OFF_LHB);   // [b][k], stride 128
    float*  rdf = (float*)(smem + OFF_RDF);
    const int ks = t >> 7;          // k-split quarter: k in [ks*32, ks*32+32)
    const int u  = t & 127;
    const int vg = u & 31;          // vocab lane; row v = v0 + vi*32 + vg
    const int bg = u >> 5;          // batch group (8 batches each)
    // stage fc_w slice into LDS once (reused for all 128 steps)
    for (int i = t; i < VW*HH_; i += 512){
      const int r = i >> 7, k = i & 127;
      ((float*)lw4)[((k >> 2)*VW + r)*4 + (k & 3)] = fcw[(size_t)(v0 + r)*HH_ + k];
    }
    float fb[5];
#pragma unroll
    for (int vi = 0; vi < 5; ++vi) fb[vi] = fcb[v0 + vi*32 + vg];
    __syncthreads();
#pragma unroll 1
    for (int s = 0; s < TT_; ++s){
      // busy-spin poll of ONE line of per-batch sentinels (wave 0 only)
      if (t < 64){
        unsigned v = (t < 32) ? 0u : 1u;
        for (;;){
          if (!v) v = aload32(&hsent[s*BB_ + t]);
          if (__all(v != 0)) break;
        }
      }
      __syncthreads();
      // PLAIN cached, coalesced h stage (16KB; per-XCD L2 multicasts across 25 wgs)
      const float4* hsrc = (const float4*)(hq + (size_t)s*BB_*HH_);
#pragma unroll
      for (int i = t; i < BB_*HH_/4; i += 512){
        const float4 v = hsrc[i];
        const int bb = i >> 5, k4 = i & 31;
        *(float4*)&lhb[bb*HH_ + k4*4] = v;
      }
      __syncthreads();
      float acc[5][8];
#pragma unroll
      for (int vi = 0; vi < 5; ++vi)
#pragma unroll
        for (int bi = 0; bi < 8; ++bi) acc[vi][bi] = 0.f;
      const int kb = ks * 8;      // 8 float4-chunks (32 k) per ks
#pragma unroll
      for (int kc = 0; kc < 8; ++kc){
        const int kcc = kb + kc;
        float4 w[5];
#pragma unroll
        for (int vi = 0; vi < 5; ++vi) w[vi] = lw4[kcc*VW + vi*32 + vg];  // read ONCE per kc
#pragma unroll
        for (int bi = 0; bi < 8; ++bi){
          const float4 hb = *(const float4*)&lhb[(bg*8 + bi)*HH_ + kcc*4];  // broadcast read
#pragma unroll
          for (int vi = 0; vi < 5; ++vi)
            acc[vi][bi] = fmaf(w[vi].x,hb.x,fmaf(w[vi].y,hb.y,fmaf(w[vi].z,hb.z,fmaf(w[vi].w,hb.w,acc[vi][bi]))));
        }
      }
      // k-split reduce: ks=1..3 publish, ks=0 combines (stride-41 dwords)
      if (ks){
        float* dst = rdf + ((size_t)(ks-1)*128 + u)*41;
#pragma unroll
        for (int vi = 0; vi < 5; ++vi)
#pragma unroll
          for (int bi = 0; bi < 8; ++bi) dst[vi*8 + bi] = acc[vi][bi];
      }
      __syncthreads();
      if (ks == 0){
#pragma unroll
        for (int r = 0; r < 3; ++r){
          const float* src = rdf + ((size_t)r*128 + u)*41;
#pragma unroll
          for (int vi = 0; vi < 5; ++vi)
#pragma unroll
            for (int bi = 0; bi < 8; ++bi) acc[vi][bi] += src[vi*8 + bi];
        }
#pragma unroll
        for (int vi = 0; vi < 5; ++vi)
#pragma unroll
          for (int bi = 0; bi < 8; ++bi) acc[vi][bi] += fb[vi];
        // per-batch argmax over this wg's 160 rows -> ONE sentinel store per (wg,batch)
#pragma unroll
        for (int bi = 0; bi < 8; ++bi){
          unsigned long long best = 0ull;
#pragma unroll
          for (int vi = 0; vi < 5; ++vi){
            const unsigned long long pk = packmax(acc[vi][bi], v0 + vi*32 + vg);
            if (pk > best) best = pk;
          }
#pragma unroll
          for (int off = 16; off > 0; off >>= 1){
            const unsigned long long o = __shfl_xor(best, off);
            if (o > best) best = o;
          }
          if (vg == 0)
            astore64(&part[((size_t)s*BB_ + bg*8 + bi)*NMM + widx], best);
        }
        // logits after publication (nontemporal; drain during next poll window)
#pragma unroll
        for (int bi = 0; bi < 8; ++bi){
          float* orow = out + ((size_t)(bg*8 + bi)*TT_ + s)*(size_t)VV_ + v0;
#pragma unroll
          for (int vi = 0; vi < 5; ++vi)
            __builtin_nontemporal_store(acc[vi][bi], &orow[vi*32 + vg]);
        }
      }
    }
  }
}

extern "C" void kernel_launch(void* const* d_in, const int* in_sizes, int n_in,
                              void* d_out, int out_size, void* d_ws, size_t ws_size,
                              hipStream_t stream){
  (void)in_sizes; (void)n_in; (void)out_size; (void)ws_size;
  const int*   x     = (const int*)  d_in[0];
  const float* embed = (const float*)d_in[1];
  const float* eWih  = (const float*)d_in[2];
  const float* eWhh  = (const float*)d_in[3];
  const float* eb    = (const float*)d_in[4];
  const float* dWih  = (const float*)d_in[5];
  const float* dWhh  = (const float*)d_in[6];
  const float* db    = (const float*)d_in[7];
  const float* fcw   = (const float*)d_in[8];
  const float* fcb   = (const float*)d_in[9];
  float* out = (float*)d_out;
  char* ws = (char*)d_ws;
  float* hq = (float*)(ws + WS_HQ);
  unsigned long long* part = (unsigned long long*)(ws + WS_PART);
  unsigned* hsent = (unsigned*)(ws + WS_HSENT);
  float* h_enc = (float*)(ws + WS_HENC);
  float* c_enc = (float*)(ws + WS_CENC);

  // zero sentinel/data buffers every launch (graph node -> deterministic replays,
  // clears the harness 0xAA poison which would defeat the sentinels)
  (void)hipMemsetAsync(ws, 0, WS_ZEND, stream);
  // allow >64KB dynamic LDS (gfx950 has 160KB/CU); idempotent host-side call
  (void)hipFuncSetAttribute((const void*)dec_kernel, hipFuncAttributeMaxDynamicSharedMemorySize, DYN_LDS);

  enc_kernel<<<NCELL, 512, 0, stream>>>(x, embed, eWih, eWhh, eb, h_enc, c_enc);
  dec_kernel<<<NWG, 512, DYN_LDS, stream>>>(embed, dWih, dWhh, db, fcw, fcb,
                                            h_enc, c_enc, hq, part, hsent, out);
}

// Round 12
// 2097.356 us; speedup vs baseline: 7.3736x; 1.0766x over previous
//
#include <hip/hip_runtime.h>
#include <math.h>

#define BB_ 32
#define TT_ 128
#define EE_ 64
#define HH_ 128
#define VV_ 32000
#define NMM 200      // matmul workgroups
#define NCELL 32     // cell workgroups (one per batch)
#define NWG (NMM + NCELL)
#define VW 160       // vocab rows per matmul wg (200*160 = 32000)

// ---- dynamic LDS layout (bytes) for matmul wgs ----
#define OFF_LW  0                   // float4[32 kcc][160 r] = 81920  fc_w slice
#define OFF_LHB 81920               // float[32 b][128 k]    = 16384  h tile
#define OFF_RDF 98304               // float[3*128]*41dw     = 62976  k-split reduce
// cell wgs overlay (same dynamic buffer, different CUs)
#define OFF_SG  0                   // float[512] gates
#define OFF_SH  2048                // float[128] h
#define OFF_TOK 2560                // int token broadcast
#define OFF_R64 2568                // u64[8] wave argmax partials
#define DYN_LDS 161280              // 157.5KB -> 1 wg/CU (160KB pool)

// ---- workspace layout (bytes) ----
// h-link: agent-atomic u32 h stores -> LLC; per-batch sentinel REPLICATED x8
//         (one 128B line per replica; 25 pollers/line instead of 200);
//         readers use PLAIN CACHED loads for h (per-XCD L2 multicast).
// part-link: data IS the sentinel (packmax nonzero); reader-contiguous [s][b][widx].
#define WS_HQ    0                                          // f32[TT][BB][HH] = 2,097,152
#define WS_PART  (TT_*BB_*HH_*4)                            // u64[TT][BB][NMM] = 6,553,600
#define WS_HSENT (WS_PART + TT_*BB_*NMM*8)                  // u32[TT][8][32] = 131,072
#define WS_ZEND  (WS_HSENT + TT_*8*32*4)                    // zero [0, WS_ZEND) each launch
#define WS_HENC  WS_ZEND                                    // f32[BB*HH]
#define WS_CENC  (WS_HENC + BB_*HH_*4)                      // f32[BB*HH]
#define WS_END   (WS_CENC + BB_*HH_*4)

__device__ __forceinline__ float rlane(float v, int l){
  return __int_as_float(__builtin_amdgcn_readlane(__float_as_int(v), l));
}
__device__ __forceinline__ float sigm(float x){ return 1.f / (1.f + expf(-x)); }

__device__ __forceinline__ unsigned long long packmax(float v, int idx){
  unsigned u = __float_as_uint(v);
  u = (u & 0x80000000u) ? ~u : (u | 0x80000000u);   // monotone float->uint map
  return ((unsigned long long)u << 32) | (unsigned long long)(0xFFFFFFFFu - (unsigned)idx);
}

__device__ __forceinline__ unsigned aload32(const unsigned* p){
  return __hip_atomic_load(p, __ATOMIC_RELAXED, __HIP_MEMORY_SCOPE_AGENT);
}
__device__ __forceinline__ unsigned long long aload64(const unsigned long long* p){
  return __hip_atomic_load(p, __ATOMIC_RELAXED, __HIP_MEMORY_SCOPE_AGENT);
}
__device__ __forceinline__ void astore32(unsigned* p, unsigned v){
  __hip_atomic_store(p, v, __ATOMIC_RELAXED, __HIP_MEMORY_SCOPE_AGENT);
}
__device__ __forceinline__ void astore64(unsigned long long* p, unsigned long long v){
  __hip_atomic_store(p, v, __ATOMIC_RELAXED, __HIP_MEMORY_SCOPE_AGENT);
}

// Whh[row t]·h : 32 float4 L2-stream + readlane broadcasts. Runs in the mm window.
__device__ __forceinline__ float whh_dot(const float* wrow, float h0, float h1){
  const float4* hp = (const float4*)wrow;
  asm volatile("" : "+v"(hp));        // opaque: keep loads inside the loop iteration
  float b0 = 0.f, b1 = 0.f, b2 = 0.f, b3 = 0.f;
#pragma unroll
  for (int q = 0; q < 16; ++q){
    const float4 w = hp[q];
    b0 = fmaf(w.x, rlane(h0, q*4+0), b0);
    b1 = fmaf(w.y, rlane(h0, q*4+1), b1);
    b2 = fmaf(w.z, rlane(h0, q*4+2), b2);
    b3 = fmaf(w.w, rlane(h0, q*4+3), b3);
  }
#pragma unroll
  for (int q = 0; q < 16; ++q){
    const float4 w = hp[16+q];
    b0 = fmaf(w.x, rlane(h1, q*4+0), b0);
    b1 = fmaf(w.y, rlane(h1, q*4+1), b1);
    b2 = fmaf(w.z, rlane(h1, q*4+2), b2);
    b3 = fmaf(w.w, rlane(h1, q*4+3), b3);
  }
  return (b0 + b1) + (b2 + b3);
}

// register-resident full gate dot (encoder)
__device__ __forceinline__ float gate_dot_r(const float (&wih)[EE_], const float (&whh)[HH_],
                                            float bias, float xe, float h0, float h1){
  float a0 = bias, a1 = 0.f, a2 = 0.f, a3 = 0.f;
#pragma unroll
  for (int e = 0; e < EE_; e += 4){
    a0 = fmaf(wih[e+0], rlane(xe, e+0), a0);
    a1 = fmaf(wih[e+1], rlane(xe, e+1), a1);
    a2 = fmaf(wih[e+2], rlane(xe, e+2), a2);
    a3 = fmaf(wih[e+3], rlane(xe, e+3), a3);
  }
#pragma unroll
  for (int j = 0; j < 64; j += 4){
    a0 = fmaf(whh[j+0], rlane(h0, j+0), a0);
    a1 = fmaf(whh[j+1], rlane(h0, j+1), a1);
    a2 = fmaf(whh[j+2], rlane(h0, j+2), a2);
    a3 = fmaf(whh[j+3], rlane(h0, j+3), a3);
  }
#pragma unroll
  for (int j = 0; j < 64; j += 4){
    a0 = fmaf(whh[64+j+0], rlane(h1, j+0), a0);
    a1 = fmaf(whh[64+j+1], rlane(h1, j+1), a1);
    a2 = fmaf(whh[64+j+2], rlane(h1, j+2), a2);
    a3 = fmaf(whh[64+j+3], rlane(h1, j+3), a3);
  }
  return (a0 + a1) + (a2 + a3);
}

// ===================== encoder: 32 wgs (one per batch), no cross-wg deps =====================
__global__ __launch_bounds__(512)
void enc_kernel(const int* __restrict__ xt, const float* __restrict__ embed,
                const float* __restrict__ Wih, const float* __restrict__ Whh,
                const float* __restrict__ bv,
                float* __restrict__ h_out, float* __restrict__ c_out)
{
  const int b = blockIdx.x, t = threadIdx.x, lane = t & 63;
  __shared__ float sh[HH_];
  __shared__ float sg[4*HH_];
  float wih[EE_], whh[HH_];
#pragma unroll
  for (int e = 0; e < EE_; ++e) wih[e] = Wih[t*EE_ + e];
#pragma unroll
  for (int j = 0; j < HH_; ++j) whh[j] = Whh[t*HH_ + j];
  const float bias = bv[t];
  float c = 0.f, hv = 0.f;
  if (t < HH_) sh[t] = 0.f;
  __syncthreads();
#pragma unroll 1
  for (int s = 0; s < TT_; ++s){
    const int tok = xt[b*TT_ + s];
    const float xe = embed[tok*EE_ + lane];
    const float h0 = sh[lane], h1 = sh[64 + lane];
    const float g = gate_dot_r(wih, whh, bias, xe, h0, h1);
    __syncthreads();   // all sh reads done
    sg[t] = g;
    __syncthreads();
    if (t < HH_){
      const float gi = sg[t], gf = sg[128+t], gg = sg[256+t], go = sg[384+t];
      c = sigm(gf)*c + sigm(gi)*tanhf(gg);
      hv = sigm(go)*tanhf(c);
      sh[t] = hv;
    }
    __syncthreads();
  }
  if (t < HH_){ h_out[b*HH_ + t] = hv; c_out[b*HH_ + t] = c; }
}

// ===================== decoder: persistent, 32 cell wgs + 200 matmul wgs =====================
__global__ __launch_bounds__(512)
void dec_kernel(const float* __restrict__ embed,
                const float* __restrict__ dWih, const float* __restrict__ dWhh,
                const float* __restrict__ db,
                const float* __restrict__ fcw, const float* __restrict__ fcb,
                const float* __restrict__ h_enc, const float* __restrict__ c_enc,
                float* __restrict__ hq, unsigned long long* __restrict__ part,
                unsigned* __restrict__ hsent, float* __restrict__ out)
{
  extern __shared__ char smem[];
  const int t = threadIdx.x;
  const int wg = blockIdx.x;

  if (wg < NCELL){
    // ---------------- cell workgroup: owns batch b (pipelined gate) ----------------
    float* sg = (float*)(smem + OFF_SG);
    float* sh = (float*)(smem + OFF_SH);
    int* stok = (int*)(smem + OFF_TOK);
    unsigned long long* r64 = (unsigned long long*)(smem + OFF_R64);
    const int b = wg, lane = t & 63;
    const float bias = db[t];
    float wih[EE_];                       // x-part weights live in REGISTERS
#pragma unroll
    for (int e = 0; e < EE_; ++e) wih[e] = dWih[t*EE_ + e];
    float c = 0.f;
    if (t < HH_){ c = c_enc[b*HH_ + t]; sh[t] = h_enc[b*HH_ + t]; }
    int tok = 1; // SOS
    __syncthreads();
    // Whh·h for the first step (h_enc), off the critical chain
    float hacc = whh_dot(dWhh + t*HH_, sh[lane], sh[64 + lane]);
#pragma unroll 1
    for (int s = 0; s < TT_; ++s){
      // token-dependent part only: 64 reg-FMAs + one (prefetched) embed row
      const float xe = embed[tok*EE_ + lane];
      float a0 = bias + hacc, a1 = 0.f, a2 = 0.f, a3 = 0.f;
#pragma unroll
      for (int e = 0; e < EE_; e += 4){
        a0 = fmaf(wih[e+0], rlane(xe, e+0), a0);
        a1 = fmaf(wih[e+1], rlane(xe, e+1), a1);
        a2 = fmaf(wih[e+2], rlane(xe, e+2), a2);
        a3 = fmaf(wih[e+3], rlane(xe, e+3), a3);
      }
      sg[t] = (a0 + a1) + (a2 + a3);
      __syncthreads();
      if (t < HH_){
        const float gi = sg[t], gf = sg[128+t], gg = sg[256+t], go = sg[384+t];
        c = sigm(gf)*c + sigm(gi)*tanhf(gg);
        const float hv = sigm(go)*tanhf(c);
        sh[t] = hv;
        __hip_atomic_store((unsigned*)&hq[(size_t)s*BB_*HH_ + b*HH_ + t],
                           __float_as_uint(hv), __ATOMIC_RELAXED, __HIP_MEMORY_SCOPE_AGENT);
      }
      __syncthreads();          // sh ready AND all waves' h stores drained (vmcnt0 at barrier)
      // bump all 8 sentinel REPLICAS in parallel (8 lanes -> 8 distinct lines)
      if (t < 8) astore32(&hsent[(s*8 + t)*32 + b], 1u);
      // overlapped with the mm window: Whh·h for the NEXT step
      const float hacc_n = whh_dot(dWhh + t*HH_, sh[lane], sh[64 + lane]);
      // busy-spin poll of this batch's 200 argmax partials (data IS the sentinel);
      // as each candidate arrives, touch its embed row -> winner is cache-hot.
      unsigned long long m = 0ull;
      if (t < NMM){
        const unsigned long long* pp = part + ((size_t)s*BB_ + b)*NMM + t;
        bool pf = false;
        for (;;){
          if (!m) m = aload64(pp);
          if (m && !pf){
            pf = true;
            const unsigned idx = 0xFFFFFFFFu - (unsigned)(m & 0xFFFFFFFFull);
            const float* er = embed + (size_t)idx*EE_;
            const float p0 = er[0], p1 = er[32];     // both 128B lines of the row
            asm volatile("" :: "v"(p0), "v"(p1));    // keep the touch loads alive
          }
          if (__all(m != 0)) break;
        }
      }
#pragma unroll
      for (int off = 32; off > 0; off >>= 1){
        const unsigned long long o = __shfl_xor(m, off);
        if (o > m) m = o;
      }
      if ((t & 63) == 0) r64[t >> 6] = m;
      __syncthreads();
      if (t == 0){
        unsigned long long best = r64[0];
#pragma unroll
        for (int w = 1; w < 8; ++w) if (r64[w] > best) best = r64[w];
        *stok = (int)(0xFFFFFFFFu - (unsigned)(best & 0xFFFFFFFFull));
      }
      __syncthreads();
      tok = *stok;
      hacc = hacc_n;
    }
  } else {
    // ---------------- matmul workgroup: vocab rows [v0, v0+VW) ----------------
    const int widx = wg - NCELL;
    const int v0 = widx * VW;
    float4* lw4 = (float4*)(smem + OFF_LW);   // [kcc][r]
    float*  lhb = (float*)(smem + OFF_LHB);   // [b][k], stride 128
    float*  rdf = (float*)(smem + OFF_RDF);
    const int ks = t >> 7;          // k-split quarter: k in [ks*32, ks*32+32)
    const int u  = t & 127;
    const int vg = u & 31;          // vocab lane; row v = v0 + vi*32 + vg
    const int bg = u >> 5;          // batch group (8 batches each)
    // stage fc_w slice into LDS once (reused for all 128 steps)
    for (int i = t; i < VW*HH_; i += 512){
      const int r = i >> 7, k = i & 127;
      ((float*)lw4)[((k >> 2)*VW + r)*4 + (k & 3)] = fcw[(size_t)(v0 + r)*HH_ + k];
    }
    float fb[5];
#pragma unroll
    for (int vi = 0; vi < 5; ++vi) fb[vi] = fcb[v0 + vi*32 + vg];
    __syncthreads();
#pragma unroll 1
    for (int s = 0; s < TT_; ++s){
      // busy-spin poll of THIS WG'S sentinel replica line (wave 0 only; 25 pollers/line)
      if (t < 64){
        unsigned v = (t < 32) ? 0u : 1u;
        const unsigned* sl = &hsent[(s*8 + (widx & 7))*32 + t];
        for (;;){
          if (!v) v = aload32(sl);
          if (__all(v != 0)) break;
        }
      }
      __syncthreads();
      // PLAIN cached, coalesced h stage (16KB; per-XCD L2 multicasts across 25 wgs)
      const float4* hsrc = (const float4*)(hq + (size_t)s*BB_*HH_);
#pragma unroll
      for (int i = t; i < BB_*HH_/4; i += 512){
        const float4 v = hsrc[i];
        const int bb = i >> 5, k4 = i & 31;
        *(float4*)&lhb[bb*HH_ + k4*4] = v;
      }
      __syncthreads();
      float acc[5][8];
#pragma unroll
      for (int vi = 0; vi < 5; ++vi)
#pragma unroll
        for (int bi = 0; bi < 8; ++bi) acc[vi][bi] = 0.f;
      const int kb = ks * 8;      // 8 float4-chunks (32 k) per ks
#pragma unroll
      for (int kc = 0; kc < 8; ++kc){
        const int kcc = kb + kc;
        float4 w[5];
#pragma unroll
        for (int vi = 0; vi < 5; ++vi) w[vi] = lw4[kcc*VW + vi*32 + vg];  // read ONCE per kc
#pragma unroll
        for (int bi = 0; bi < 8; ++bi){
          const float4 hb = *(const float4*)&lhb[(bg*8 + bi)*HH_ + kcc*4];  // broadcast read
#pragma unroll
          for (int vi = 0; vi < 5; ++vi)
            acc[vi][bi] = fmaf(w[vi].x,hb.x,fmaf(w[vi].y,hb.y,fmaf(w[vi].z,hb.z,fmaf(w[vi].w,hb.w,acc[vi][bi]))));
        }
      }
      // k-split reduce: ks=1..3 publish, ks=0 combines (stride-41 dwords)
      if (ks){
        float* dst = rdf + ((size_t)(ks-1)*128 + u)*41;
#pragma unroll
        for (int vi = 0; vi < 5; ++vi)
#pragma unroll
          for (int bi = 0; bi < 8; ++bi) dst[vi*8 + bi] = acc[vi][bi];
      }
      __syncthreads();
      if (ks == 0){
#pragma unroll
        for (int r = 0; r < 3; ++r){
          const float* src = rdf + ((size_t)r*128 + u)*41;
#pragma unroll
          for (int vi = 0; vi < 5; ++vi)
#pragma unroll
            for (int bi = 0; bi < 8; ++bi) acc[vi][bi] += src[vi*8 + bi];
        }
#pragma unroll
        for (int vi = 0; vi < 5; ++vi)
#pragma unroll
          for (int bi = 0; bi < 8; ++bi) acc[vi][bi] += fb[vi];
        // per-batch argmax over this wg's 160 rows -> ONE sentinel store per (wg,batch)
#pragma unroll
        for (int bi = 0; bi < 8; ++bi){
          unsigned long long best = 0ull;
#pragma unroll
          for (int vi = 0; vi < 5; ++vi){
            const unsigned long long pk = packmax(acc[vi][bi], v0 + vi*32 + vg);
            if (pk > best) best = pk;
          }
#pragma unroll
          for (int off = 16; off > 0; off >>= 1){
            const unsigned long long o = __shfl_xor(best, off);
            if (o > best) best = o;
          }
          if (vg == 0)
            astore64(&part[((size_t)s*BB_ + bg*8 + bi)*NMM + widx], best);
        }
        // logits after publication (nontemporal; drain during next poll window)
#pragma unroll
        for (int bi = 0; bi < 8; ++bi){
          float* orow = out + ((size_t)(bg*8 + bi)*TT_ + s)*(size_t)VV_ + v0;
#pragma unroll
          for (int vi = 0; vi < 5; ++vi)
            __builtin_nontemporal_store(acc[vi][bi], &orow[vi*32 + vg]);
        }
      }
    }
  }
}

extern "C" void kernel_launch(void* const* d_in, const int* in_sizes, int n_in,
                              void* d_out, int out_size, void* d_ws, size_t ws_size,
                              hipStream_t stream){
  (void)in_sizes; (void)n_in; (void)out_size; (void)ws_size;
  const int*   x     = (const int*)  d_in[0];
  const float* embed = (const float*)d_in[1];
  const float* eWih  = (const float*)d_in[2];
  const float* eWhh  = (const float*)d_in[3];
  const float* eb    = (const float*)d_in[4];
  const float* dWih  = (const float*)d_in[5];
  const float* dWhh  = (const float*)d_in[6];
  const float* db    = (const float*)d_in[7];
  const float* fcw   = (const float*)d_in[8];
  const float* fcb   = (const float*)d_in[9];
  float* out = (float*)d_out;
  char* ws = (char*)d_ws;
  float* hq = (float*)(ws + WS_HQ);
  unsigned long long* part = (unsigned long long*)(ws + WS_PART);
  unsigned* hsent = (unsigned*)(ws + WS_HSENT);
  float* h_enc = (float*)(ws + WS_HENC);
  float* c_enc = (float*)(ws + WS_CENC);

  // zero sentinel/data buffers every launch (graph node -> deterministic replays,
  // clears the harness 0xAA poison which would defeat the sentinels)
  (void)hipMemsetAsync(ws, 0, WS_ZEND, stream);
  // allow >64KB dynamic LDS (gfx950 has 160KB/CU); idempotent host-side call
  (void)hipFuncSetAttribute((const void*)dec_kernel, hipFuncAttributeMaxDynamicSharedMemorySize, DYN_LDS);

  enc_kernel<<<NCELL, 512, 0, stream>>>(x, embed, eWih, eWhh, eb, h_enc, c_enc);
  dec_kernel<<<NWG, 512, DYN_LDS, stream>>>(embed, dWih, dWhh, db, fcw, fcb,
                                            h_enc, c_enc, hq, part, hsent, out);
}